// Round 1
// baseline (774.361 us; speedup 1.0000x reference)
//
#include <hip/hip_runtime.h>

#define N_NODES 40000
#define E_EDGES 640000
#define E_TOT   (E_EDGES + N_NODES)

// ---------------------------------------------------------------------------
// GEMM1: h1 = x @ W1   [40000x128 @ 128x128], fused per-node attention coeffs
// al_src[n,h] = sum_c h1[n,h*32+c]*a_src[h,c]  (same for a_dst)
// Block: 64 rows x 128 cols, 256 threads, each thread 4x8 outputs.
// ---------------------------------------------------------------------------
__global__ __launch_bounds__(256) void gemm1_kernel(
    const float* __restrict__ x, const float* __restrict__ W,
    const float* __restrict__ a_src, const float* __restrict__ a_dst,
    float* __restrict__ h1, float* __restrict__ asrc, float* __restrict__ adst)
{
    __shared__ float Ws[128 * 128];   // 64 KB
    {
        const float4* Wg = (const float4*)W;
        float4* Wl = (float4*)Ws;
        for (int i = threadIdx.x; i < 128 * 128 / 4; i += 256) Wl[i] = Wg[i];
    }
    __syncthreads();
    const int row0 = blockIdx.x * 64;
    const int tx = threadIdx.x & 15;   // 16 col-groups of 8 cols
    const int ty = threadIdx.x >> 4;   // 16 row-groups of 4 rows

    float acc[4][8];
#pragma unroll
    for (int r = 0; r < 4; ++r)
#pragma unroll
        for (int c = 0; c < 8; ++c) acc[r][c] = 0.f;

    for (int k0 = 0; k0 < 128; k0 += 4) {
        float xv[4][4];
#pragma unroll
        for (int r = 0; r < 4; ++r) {
            float4 t = *(const float4*)&x[(size_t)(row0 + ty * 4 + r) * 128 + k0];
            xv[r][0] = t.x; xv[r][1] = t.y; xv[r][2] = t.z; xv[r][3] = t.w;
        }
#pragma unroll
        for (int kk = 0; kk < 4; ++kk) {
            float wreg[8];
            float4 w0 = *(const float4*)&Ws[(k0 + kk) * 128 + tx * 8];
            float4 w1 = *(const float4*)&Ws[(k0 + kk) * 128 + tx * 8 + 4];
            wreg[0] = w0.x; wreg[1] = w0.y; wreg[2] = w0.z; wreg[3] = w0.w;
            wreg[4] = w1.x; wreg[5] = w1.y; wreg[6] = w1.z; wreg[7] = w1.w;
#pragma unroll
            for (int r = 0; r < 4; ++r)
#pragma unroll
                for (int c = 0; c < 8; ++c)
                    acc[r][c] = fmaf(xv[r][kk], wreg[c], acc[r][c]);
        }
    }

    const int head  = tx >> 2;          // cols tx*8 -> head = tx/4
    const int cbase = (tx & 3) * 8;     // offset within the head's 32 channels
    float as[8], ad[8];
#pragma unroll
    for (int c = 0; c < 8; ++c) {
        as[c] = a_src[head * 32 + cbase + c];
        ad[c] = a_dst[head * 32 + cbase + c];
    }
#pragma unroll
    for (int r = 0; r < 4; ++r) {
        const int n = row0 + ty * 4 + r;
        float4 o0 = make_float4(acc[r][0], acc[r][1], acc[r][2], acc[r][3]);
        float4 o1 = make_float4(acc[r][4], acc[r][5], acc[r][6], acc[r][7]);
        *(float4*)&h1[(size_t)n * 128 + tx * 8]     = o0;
        *(float4*)&h1[(size_t)n * 128 + tx * 8 + 4] = o1;
        float ps = 0.f, pd = 0.f;
#pragma unroll
        for (int c = 0; c < 8; ++c) {
            ps = fmaf(acc[r][c], as[c], ps);
            pd = fmaf(acc[r][c], ad[c], pd);
        }
        // reduce over the 4 lanes (tx&3) covering one head
        ps += __shfl_xor(ps, 1); ps += __shfl_xor(ps, 2);
        pd += __shfl_xor(pd, 1); pd += __shfl_xor(pd, 2);
        if ((threadIdx.x & 3) == 0) {
            asrc[n * 4 + head] = ps;
            adst[n * 4 + head] = pd;
        }
    }
}

// ---------------------------------------------------------------------------
// Edge pass 1: one wave per edge, 64 lanes x float2 = 128 channels.
// ex = exp(leaky_relu(asrc[s,h]+adst[d,h])); den[d,h] += ex; agg[d,:] += ex*h1[s,:]
// (max-subtraction skipped: mathematically identical, |e| << 88)
// ---------------------------------------------------------------------------
__global__ __launch_bounds__(256) void edge1_kernel(
    const int* __restrict__ eidx, const float* __restrict__ asrc,
    const float* __restrict__ adst, const float* __restrict__ h1,
    float* __restrict__ den, float* __restrict__ agg)
{
    const int wave = (blockIdx.x * 256 + threadIdx.x) >> 6;
    const int lane = threadIdx.x & 63;
    if (wave >= E_TOT) return;
    int s, d;
    if (wave < E_EDGES) { s = eidx[wave]; d = eidx[E_EDGES + wave]; }
    else                { s = d = wave - E_EDGES; }
    const int head = lane >> 4;
    float av = asrc[s * 4 + head] + adst[d * 4 + head];
    av = av > 0.f ? av : 0.2f * av;
    const float ex = __expf(av);
    const float2 hv = *(const float2*)&h1[(size_t)s * 128 + lane * 2];
    if ((lane & 15) == 0) atomicAdd(&den[d * 4 + head], ex);
    atomicAdd(&agg[(size_t)d * 128 + lane * 2],     ex * hv.x);
    atomicAdd(&agg[(size_t)d * 128 + lane * 2 + 1], ex * hv.y);
}

// ---------------------------------------------------------------------------
// Normalize 1: agg = elu(agg/(den+1e-16) + b1), in place. float4 per thread.
// ---------------------------------------------------------------------------
__global__ __launch_bounds__(256) void norm1_kernel(
    float* __restrict__ agg, const float* __restrict__ den,
    const float* __restrict__ b)
{
    const int t = blockIdx.x * 256 + threadIdx.x;   // 1,280,000 threads
    const int base = t * 4;
    const int n = base >> 7;
    const int hc = base & 127;
    const int head = hc >> 5;
    const float dv = den[n * 4 + head] + 1e-16f;
    float4 v = *(float4*)&agg[base];
    const float4 bv = *(const float4*)&b[hc];
    float o[4] = { v.x / dv + bv.x, v.y / dv + bv.y, v.z / dv + bv.z, v.w / dv + bv.w };
#pragma unroll
    for (int i = 0; i < 4; ++i) o[i] = o[i] > 0.f ? o[i] : expm1f(o[i]);
    *(float4*)&agg[base] = make_float4(o[0], o[1], o[2], o[3]);
}

// ---------------------------------------------------------------------------
// GEMM2: h2 = hin @ W2  [40000x128 @ 128x32], fused attention coeffs (1 head)
// Block: 64 rows x 32 cols, 256 threads, each thread 2x4 outputs.
// ---------------------------------------------------------------------------
__global__ __launch_bounds__(256) void gemm2_kernel(
    const float* __restrict__ hin, const float* __restrict__ W,
    const float* __restrict__ a_src, const float* __restrict__ a_dst,
    float* __restrict__ h2, float* __restrict__ asrc, float* __restrict__ adst)
{
    __shared__ float Ws[128 * 32];   // 16 KB
    {
        const float4* Wg = (const float4*)W;
        float4* Wl = (float4*)Ws;
        for (int i = threadIdx.x; i < 128 * 32 / 4; i += 256) Wl[i] = Wg[i];
    }
    __syncthreads();
    const int row0 = blockIdx.x * 64;
    const int tx = threadIdx.x & 7;    // 8 col-groups of 4
    const int ty = threadIdx.x >> 3;   // 32 row-groups of 2

    float acc[2][4];
#pragma unroll
    for (int r = 0; r < 2; ++r)
#pragma unroll
        for (int c = 0; c < 4; ++c) acc[r][c] = 0.f;

    for (int k0 = 0; k0 < 128; k0 += 4) {
        float xv[2][4];
#pragma unroll
        for (int r = 0; r < 2; ++r) {
            float4 t = *(const float4*)&hin[(size_t)(row0 + ty * 2 + r) * 128 + k0];
            xv[r][0] = t.x; xv[r][1] = t.y; xv[r][2] = t.z; xv[r][3] = t.w;
        }
#pragma unroll
        for (int kk = 0; kk < 4; ++kk) {
            float4 w = *(const float4*)&Ws[(k0 + kk) * 32 + tx * 4];
            float wreg[4] = { w.x, w.y, w.z, w.w };
#pragma unroll
            for (int r = 0; r < 2; ++r)
#pragma unroll
                for (int c = 0; c < 4; ++c)
                    acc[r][c] = fmaf(xv[r][kk], wreg[c], acc[r][c]);
        }
    }

    float as[4], ad[4];
#pragma unroll
    for (int c = 0; c < 4; ++c) {
        as[c] = a_src[tx * 4 + c];
        ad[c] = a_dst[tx * 4 + c];
    }
#pragma unroll
    for (int r = 0; r < 2; ++r) {
        const int n = row0 + ty * 2 + r;
        *(float4*)&h2[(size_t)n * 32 + tx * 4] =
            make_float4(acc[r][0], acc[r][1], acc[r][2], acc[r][3]);
        float ps = 0.f, pd = 0.f;
#pragma unroll
        for (int c = 0; c < 4; ++c) {
            ps = fmaf(acc[r][c], as[c], ps);
            pd = fmaf(acc[r][c], ad[c], pd);
        }
        ps += __shfl_xor(ps, 1); ps += __shfl_xor(ps, 2); ps += __shfl_xor(ps, 4);
        pd += __shfl_xor(pd, 1); pd += __shfl_xor(pd, 2); pd += __shfl_xor(pd, 4);
        if ((threadIdx.x & 7) == 0) { asrc[n] = ps; adst[n] = pd; }
    }
}

// ---------------------------------------------------------------------------
// Edge pass 2: 32 threads per edge (1 head, 32 channels).
// ---------------------------------------------------------------------------
__global__ __launch_bounds__(256) void edge2_kernel(
    const int* __restrict__ eidx, const float* __restrict__ asrc,
    const float* __restrict__ adst, const float* __restrict__ h2,
    float* __restrict__ den, float* __restrict__ agg)
{
    const int t = blockIdx.x * 256 + threadIdx.x;
    const int e = t >> 5;
    const int c = t & 31;
    if (e >= E_TOT) return;
    int s, d;
    if (e < E_EDGES) { s = eidx[e]; d = eidx[E_EDGES + e]; }
    else             { s = d = e - E_EDGES; }
    float av = asrc[s] + adst[d];
    av = av > 0.f ? av : 0.2f * av;
    const float ex = __expf(av);
    if (c == 0) atomicAdd(&den[d], ex);
    atomicAdd(&agg[(size_t)d * 32 + c], ex * h2[(size_t)s * 32 + c]);
}

// ---------------------------------------------------------------------------
// Normalize 2: agg2 = elu(agg2/(den2+1e-16) + b2), in place.
// ---------------------------------------------------------------------------
__global__ __launch_bounds__(256) void norm2_kernel(
    float* __restrict__ agg, const float* __restrict__ den,
    const float* __restrict__ b)
{
    const int t = blockIdx.x * 256 + threadIdx.x;   // 320,000 threads
    const int base = t * 4;
    const int n = base >> 5;
    const int c = base & 31;
    const float dv = den[n] + 1e-16f;
    float4 v = *(float4*)&agg[base];
    const float4 bv = *(const float4*)&b[c];
    float o[4] = { v.x / dv + bv.x, v.y / dv + bv.y, v.z / dv + bv.z, v.w / dv + bv.w };
#pragma unroll
    for (int i = 0; i < 4; ++i) o[i] = o[i] > 0.f ? o[i] : expm1f(o[i]);
    *(float4*)&agg[base] = make_float4(o[0], o[1], o[2], o[3]);
}

// ---------------------------------------------------------------------------
// Output GEMM: out = h3 @ W_out + b_out  [40000x32 @ 32x112]
// Block: 32 rows x 112 cols, 256 threads (16 colgroups x 7, 16 rowgroups x 2).
// ---------------------------------------------------------------------------
__global__ __launch_bounds__(256) void out_gemm_kernel(
    const float* __restrict__ h3, const float* __restrict__ W,
    const float* __restrict__ b, float* __restrict__ out)
{
    __shared__ float Ws[32 * 112];   // 14 KB
    {
        const float4* Wg = (const float4*)W;
        float4* Wl = (float4*)Ws;
        for (int i = threadIdx.x; i < 32 * 112 / 4; i += 256) Wl[i] = Wg[i];
    }
    __syncthreads();
    const int row0 = blockIdx.x * 32;
    const int tc = threadIdx.x & 15;   // 7 cols each
    const int tr = threadIdx.x >> 4;   // 2 rows each

    float acc[2][7];
#pragma unroll
    for (int r = 0; r < 2; ++r)
#pragma unroll
        for (int c = 0; c < 7; ++c) acc[r][c] = 0.f;

    for (int k0 = 0; k0 < 32; k0 += 4) {
        float xv[2][4];
#pragma unroll
        for (int r = 0; r < 2; ++r) {
            float4 t = *(const float4*)&h3[(size_t)(row0 + tr * 2 + r) * 32 + k0];
            xv[r][0] = t.x; xv[r][1] = t.y; xv[r][2] = t.z; xv[r][3] = t.w;
        }
#pragma unroll
        for (int kk = 0; kk < 4; ++kk) {
            float wv[7];
#pragma unroll
            for (int c = 0; c < 7; ++c) wv[c] = Ws[(k0 + kk) * 112 + tc * 7 + c];
#pragma unroll
            for (int r = 0; r < 2; ++r)
#pragma unroll
                for (int c = 0; c < 7; ++c)
                    acc[r][c] = fmaf(xv[r][kk], wv[c], acc[r][c]);
        }
    }
#pragma unroll
    for (int r = 0; r < 2; ++r) {
        const int n = row0 + tr * 2 + r;
#pragma unroll
        for (int c = 0; c < 7; ++c)
            out[(size_t)n * 112 + tc * 7 + c] = acc[r][c] + b[tc * 7 + c];
    }
}

// ---------------------------------------------------------------------------
extern "C" void kernel_launch(void* const* d_in, const int* in_sizes, int n_in,
                              void* d_out, int out_size, void* d_ws, size_t ws_size,
                              hipStream_t stream) {
    const float* x      = (const float*)d_in[0];
    const int*   eidx   = (const int*)d_in[1];
    const float* W1     = (const float*)d_in[2];
    const float* a_src1 = (const float*)d_in[3];
    const float* a_dst1 = (const float*)d_in[4];
    const float* b1     = (const float*)d_in[5];
    const float* W2     = (const float*)d_in[6];
    const float* a_src2 = (const float*)d_in[7];
    const float* a_dst2 = (const float*)d_in[8];
    const float* b2     = (const float*)d_in[9];
    const float* W_out  = (const float*)d_in[10];
    const float* b_out  = (const float*)d_in[11];
    float* out = (float*)d_out;

    float* ws    = (float*)d_ws;
    float* h1    = ws;                    // 40000*128
    float* asrc1 = h1 + 5120000;          // 40000*4
    float* adst1 = asrc1 + 160000;        // 40000*4
    float* den1  = adst1 + 160000;        // 40000*4
    float* agg1  = den1 + 160000;         // 40000*128
    float* h2    = agg1 + 5120000;        // 40000*32
    float* asrc2 = h2 + 1280000;          // 40000
    float* adst2 = asrc2 + 40000;         // 40000
    float* den2  = adst2 + 40000;         // 40000
    float* agg2  = den2 + 40000;          // 40000*32

    // zero the accumulators (den1+agg1 contiguous, den2+agg2 contiguous)
    hipMemsetAsync(den1, 0, (size_t)(160000 + 5120000) * sizeof(float), stream);
    hipMemsetAsync(den2, 0, (size_t)(40000 + 1280000) * sizeof(float), stream);

    gemm1_kernel<<<625, 256, 0, stream>>>(x, W1, a_src1, a_dst1, h1, asrc1, adst1);
    edge1_kernel<<<E_TOT / 4, 256, 0, stream>>>(eidx, asrc1, adst1, h1, den1, agg1);
    norm1_kernel<<<5000, 256, 0, stream>>>(agg1, den1, b1);
    gemm2_kernel<<<625, 256, 0, stream>>>(agg1, W2, a_src2, a_dst2, h2, asrc2, adst2);
    edge2_kernel<<<E_TOT * 32 / 256, 256, 0, stream>>>(eidx, asrc2, adst2, h2, den2, agg2);
    norm2_kernel<<<1250, 256, 0, stream>>>(agg2, den2, b2);
    out_gemm_kernel<<<1250, 256, 0, stream>>>(agg2, W_out, b_out, out);
}

// Round 2
// 312.914 us; speedup vs baseline: 2.4747x; 2.4747x over previous
//
#include <hip/hip_runtime.h>

#define N_NODES 40000
#define E_EDGES 640000
#define E_TOT   (E_EDGES + N_NODES)

// ===========================================================================
// CSR build: histogram -> single-block exclusive scan -> fill (bucket sort by
// dst). Built once per call, reused by both GAT layers.
// ===========================================================================
__global__ __launch_bounds__(256) void hist_kernel(
    const int* __restrict__ eidx, int* __restrict__ cnt)
{
    const int e = blockIdx.x * 256 + threadIdx.x;
    if (e >= E_TOT) return;
    const int d = (e < E_EDGES) ? eidx[E_EDGES + e] : e - E_EDGES;
    atomicAdd(&cnt[d], 1);
}

// One block, 1024 threads. Exclusive scan of cnt[0..N) into rowptr[0..N],
// zeroes cnt for reuse as the fill cursor.
__global__ __launch_bounds__(1024) void scan_kernel(
    int* __restrict__ cnt, int* __restrict__ rowptr)
{
    __shared__ int sm[1024];
    __shared__ int run;
    if (threadIdx.x == 0) run = 0;
    __syncthreads();
    const int nchunk = (N_NODES + 1023) / 1024;
    for (int chunk = 0; chunk < nchunk; ++chunk) {
        const int i = chunk * 1024 + threadIdx.x;
        int v = (i < N_NODES) ? cnt[i] : 0;
        if (i < N_NODES) cnt[i] = 0;
        sm[threadIdx.x] = v;
        __syncthreads();
        for (int off = 1; off < 1024; off <<= 1) {
            int t = (threadIdx.x >= off) ? sm[threadIdx.x - off] : 0;
            __syncthreads();
            sm[threadIdx.x] += t;
            __syncthreads();
        }
        const int incl = sm[threadIdx.x];
        const int base = run;
        if (i < N_NODES) rowptr[i] = base + incl - v;
        __syncthreads();
        if (threadIdx.x == 1023) run = base + incl;
        __syncthreads();
    }
    if (threadIdx.x == 0) rowptr[N_NODES] = run;
}

__global__ __launch_bounds__(256) void fill_kernel(
    const int* __restrict__ eidx, const int* __restrict__ rowptr,
    int* __restrict__ cursor, int* __restrict__ esrc)
{
    const int e = blockIdx.x * 256 + threadIdx.x;
    if (e >= E_TOT) return;
    int s, d;
    if (e < E_EDGES) { s = eidx[e]; d = eidx[E_EDGES + e]; }
    else             { s = d = e - E_EDGES; }
    const int pos = atomicAdd(&cursor[d], 1);
    esrc[rowptr[d] + pos] = s;
}

// ===========================================================================
// GEMM1: h1 = x @ W1   [40000x128 @ 128x128], fused per-node attention coeffs
// ===========================================================================
__global__ __launch_bounds__(256) void gemm1_kernel(
    const float* __restrict__ x, const float* __restrict__ W,
    const float* __restrict__ a_src, const float* __restrict__ a_dst,
    float* __restrict__ h1, float* __restrict__ asrc, float* __restrict__ adst)
{
    __shared__ float Ws[128 * 128];   // 64 KB
    {
        const float4* Wg = (const float4*)W;
        float4* Wl = (float4*)Ws;
        for (int i = threadIdx.x; i < 128 * 128 / 4; i += 256) Wl[i] = Wg[i];
    }
    __syncthreads();
    const int row0 = blockIdx.x * 64;
    const int tx = threadIdx.x & 15;   // 16 col-groups of 8 cols
    const int ty = threadIdx.x >> 4;   // 16 row-groups of 4 rows

    float acc[4][8];
#pragma unroll
    for (int r = 0; r < 4; ++r)
#pragma unroll
        for (int c = 0; c < 8; ++c) acc[r][c] = 0.f;

    for (int k0 = 0; k0 < 128; k0 += 4) {
        float xv[4][4];
#pragma unroll
        for (int r = 0; r < 4; ++r) {
            float4 t = *(const float4*)&x[(size_t)(row0 + ty * 4 + r) * 128 + k0];
            xv[r][0] = t.x; xv[r][1] = t.y; xv[r][2] = t.z; xv[r][3] = t.w;
        }
#pragma unroll
        for (int kk = 0; kk < 4; ++kk) {
            float wreg[8];
            float4 w0 = *(const float4*)&Ws[(k0 + kk) * 128 + tx * 8];
            float4 w1 = *(const float4*)&Ws[(k0 + kk) * 128 + tx * 8 + 4];
            wreg[0] = w0.x; wreg[1] = w0.y; wreg[2] = w0.z; wreg[3] = w0.w;
            wreg[4] = w1.x; wreg[5] = w1.y; wreg[6] = w1.z; wreg[7] = w1.w;
#pragma unroll
            for (int r = 0; r < 4; ++r)
#pragma unroll
                for (int c = 0; c < 8; ++c)
                    acc[r][c] = fmaf(xv[r][kk], wreg[c], acc[r][c]);
        }
    }

    const int head  = tx >> 2;
    const int cbase = (tx & 3) * 8;
    float as[8], ad[8];
#pragma unroll
    for (int c = 0; c < 8; ++c) {
        as[c] = a_src[head * 32 + cbase + c];
        ad[c] = a_dst[head * 32 + cbase + c];
    }
#pragma unroll
    for (int r = 0; r < 4; ++r) {
        const int n = row0 + ty * 4 + r;
        *(float4*)&h1[(size_t)n * 128 + tx * 8] =
            make_float4(acc[r][0], acc[r][1], acc[r][2], acc[r][3]);
        *(float4*)&h1[(size_t)n * 128 + tx * 8 + 4] =
            make_float4(acc[r][4], acc[r][5], acc[r][6], acc[r][7]);
        float ps = 0.f, pd = 0.f;
#pragma unroll
        for (int c = 0; c < 8; ++c) {
            ps = fmaf(acc[r][c], as[c], ps);
            pd = fmaf(acc[r][c], ad[c], pd);
        }
        ps += __shfl_xor(ps, 1); ps += __shfl_xor(ps, 2);
        pd += __shfl_xor(pd, 1); pd += __shfl_xor(pd, 2);
        if ((threadIdx.x & 3) == 0) {
            asrc[n * 4 + head] = ps;
            adst[n * 4 + head] = pd;
        }
    }
}

// ===========================================================================
// Gather pass 1: one wave per dst node. Walk CSR in-edges, accumulate
// softmax-weighted h1[src] in registers; fused normalize + bias + ELU.
// (max-subtraction skipped: exp(e)/sum(exp(e)) identical, |e| << 88)
// ===========================================================================
__global__ __launch_bounds__(256) void gather1_kernel(
    const int* __restrict__ rowptr, const int* __restrict__ esrc,
    const float* __restrict__ asrc, const float* __restrict__ adst,
    const float* __restrict__ h1, const float* __restrict__ b,
    float* __restrict__ agg)
{
    const int node = (blockIdx.x * 256 + threadIdx.x) >> 6;
    const int lane = threadIdx.x & 63;
    if (node >= N_NODES) return;
    const int head = lane >> 4;
    const float ad = adst[node * 4 + head];
    const int beg = rowptr[node], end = rowptr[node + 1];
    float acc0 = 0.f, acc1 = 0.f, den = 0.f;
    for (int i = beg; i < end; ++i) {
        const int s = esrc[i];
        float av = asrc[s * 4 + head] + ad;
        av = av > 0.f ? av : 0.2f * av;
        const float ex = __expf(av);
        const float2 hv = *(const float2*)&h1[(size_t)s * 128 + lane * 2];
        den += ex;
        acc0 = fmaf(ex, hv.x, acc0);
        acc1 = fmaf(ex, hv.y, acc1);
    }
    const float inv = 1.f / (den + 1e-16f);
    const float2 bv = *(const float2*)&b[lane * 2];
    float o0 = acc0 * inv + bv.x;
    float o1 = acc1 * inv + bv.y;
    o0 = o0 > 0.f ? o0 : expm1f(o0);
    o1 = o1 > 0.f ? o1 : expm1f(o1);
    *(float2*)&agg[(size_t)node * 128 + lane * 2] = make_float2(o0, o1);
}

// ===========================================================================
// GEMM2: h2 = hin @ W2  [40000x128 @ 128x32], fused attention coeffs (1 head)
// ===========================================================================
__global__ __launch_bounds__(256) void gemm2_kernel(
    const float* __restrict__ hin, const float* __restrict__ W,
    const float* __restrict__ a_src, const float* __restrict__ a_dst,
    float* __restrict__ h2, float* __restrict__ asrc, float* __restrict__ adst)
{
    __shared__ float Ws[128 * 32];   // 16 KB
    {
        const float4* Wg = (const float4*)W;
        float4* Wl = (float4*)Ws;
        for (int i = threadIdx.x; i < 128 * 32 / 4; i += 256) Wl[i] = Wg[i];
    }
    __syncthreads();
    const int row0 = blockIdx.x * 64;
    const int tx = threadIdx.x & 7;
    const int ty = threadIdx.x >> 3;

    float acc[2][4];
#pragma unroll
    for (int r = 0; r < 2; ++r)
#pragma unroll
        for (int c = 0; c < 4; ++c) acc[r][c] = 0.f;

    for (int k0 = 0; k0 < 128; k0 += 4) {
        float xv[2][4];
#pragma unroll
        for (int r = 0; r < 2; ++r) {
            float4 t = *(const float4*)&hin[(size_t)(row0 + ty * 2 + r) * 128 + k0];
            xv[r][0] = t.x; xv[r][1] = t.y; xv[r][2] = t.z; xv[r][3] = t.w;
        }
#pragma unroll
        for (int kk = 0; kk < 4; ++kk) {
            float4 w = *(const float4*)&Ws[(k0 + kk) * 32 + tx * 4];
            float wreg[4] = { w.x, w.y, w.z, w.w };
#pragma unroll
            for (int r = 0; r < 2; ++r)
#pragma unroll
                for (int c = 0; c < 4; ++c)
                    acc[r][c] = fmaf(xv[r][kk], wreg[c], acc[r][c]);
        }
    }

    float as[4], ad[4];
#pragma unroll
    for (int c = 0; c < 4; ++c) {
        as[c] = a_src[tx * 4 + c];
        ad[c] = a_dst[tx * 4 + c];
    }
#pragma unroll
    for (int r = 0; r < 2; ++r) {
        const int n = row0 + ty * 2 + r;
        *(float4*)&h2[(size_t)n * 32 + tx * 4] =
            make_float4(acc[r][0], acc[r][1], acc[r][2], acc[r][3]);
        float ps = 0.f, pd = 0.f;
#pragma unroll
        for (int c = 0; c < 4; ++c) {
            ps = fmaf(acc[r][c], as[c], ps);
            pd = fmaf(acc[r][c], ad[c], pd);
        }
        ps += __shfl_xor(ps, 1); ps += __shfl_xor(ps, 2); ps += __shfl_xor(ps, 4);
        pd += __shfl_xor(pd, 1); pd += __shfl_xor(pd, 2); pd += __shfl_xor(pd, 4);
        if ((threadIdx.x & 7) == 0) { asrc[n] = ps; adst[n] = pd; }
    }
}

// ===========================================================================
// Gather pass 2: 32 lanes per dst node (2 nodes/wave); fused norm+bias+ELU.
// ===========================================================================
__global__ __launch_bounds__(256) void gather2_kernel(
    const int* __restrict__ rowptr, const int* __restrict__ esrc,
    const float* __restrict__ asrc, const float* __restrict__ adst,
    const float* __restrict__ h2, const float* __restrict__ b,
    float* __restrict__ agg)
{
    const int t = blockIdx.x * 256 + threadIdx.x;
    const int node = t >> 5;
    const int c = t & 31;
    if (node >= N_NODES) return;
    const float ad = adst[node];
    const int beg = rowptr[node], end = rowptr[node + 1];
    float acc = 0.f, den = 0.f;
    for (int i = beg; i < end; ++i) {
        const int s = esrc[i];
        float av = asrc[s] + ad;
        av = av > 0.f ? av : 0.2f * av;
        const float ex = __expf(av);
        den += ex;
        acc = fmaf(ex, h2[(size_t)s * 32 + c], acc);
    }
    const float inv = 1.f / (den + 1e-16f);
    float o = acc * inv + b[c];
    o = o > 0.f ? o : expm1f(o);
    agg[(size_t)node * 32 + c] = o;
}

// ===========================================================================
// Output GEMM: out = h3 @ W_out + b_out  [40000x32 @ 32x112]
// ===========================================================================
__global__ __launch_bounds__(256) void out_gemm_kernel(
    const float* __restrict__ h3, const float* __restrict__ W,
    const float* __restrict__ b, float* __restrict__ out)
{
    __shared__ float Ws[32 * 112];   // 14 KB
    {
        const float4* Wg = (const float4*)W;
        float4* Wl = (float4*)Ws;
        for (int i = threadIdx.x; i < 32 * 112 / 4; i += 256) Wl[i] = Wg[i];
    }
    __syncthreads();
    const int row0 = blockIdx.x * 32;
    const int tc = threadIdx.x & 15;
    const int tr = threadIdx.x >> 4;

    float acc[2][7];
#pragma unroll
    for (int r = 0; r < 2; ++r)
#pragma unroll
        for (int c = 0; c < 7; ++c) acc[r][c] = 0.f;

    for (int k0 = 0; k0 < 32; k0 += 4) {
        float xv[2][4];
#pragma unroll
        for (int r = 0; r < 2; ++r) {
            float4 t = *(const float4*)&h3[(size_t)(row0 + tr * 2 + r) * 32 + k0];
            xv[r][0] = t.x; xv[r][1] = t.y; xv[r][2] = t.z; xv[r][3] = t.w;
        }
#pragma unroll
        for (int kk = 0; kk < 4; ++kk) {
            float wv[7];
#pragma unroll
            for (int c = 0; c < 7; ++c) wv[c] = Ws[(k0 + kk) * 112 + tc * 7 + c];
#pragma unroll
            for (int r = 0; r < 2; ++r)
#pragma unroll
                for (int c = 0; c < 7; ++c)
                    acc[r][c] = fmaf(xv[r][kk], wv[c], acc[r][c]);
        }
    }
#pragma unroll
    for (int r = 0; r < 2; ++r) {
        const int n = row0 + tr * 2 + r;
#pragma unroll
        for (int c = 0; c < 7; ++c)
            out[(size_t)n * 112 + tc * 7 + c] = acc[r][c] + b[tc * 7 + c];
    }
}

// ===========================================================================
extern "C" void kernel_launch(void* const* d_in, const int* in_sizes, int n_in,
                              void* d_out, int out_size, void* d_ws, size_t ws_size,
                              hipStream_t stream) {
    const float* x      = (const float*)d_in[0];
    const int*   eidx   = (const int*)d_in[1];
    const float* W1     = (const float*)d_in[2];
    const float* a_src1 = (const float*)d_in[3];
    const float* a_dst1 = (const float*)d_in[4];
    const float* b1     = (const float*)d_in[5];
    const float* W2     = (const float*)d_in[6];
    const float* a_src2 = (const float*)d_in[7];
    const float* a_dst2 = (const float*)d_in[8];
    const float* b2     = (const float*)d_in[9];
    const float* W_out  = (const float*)d_in[10];
    const float* b_out  = (const float*)d_in[11];
    float* out = (float*)d_out;

    // ---- workspace layout (45.3 MB) ----
    int* rowptr = (int*)d_ws;             // 40001 (padded 40064)
    int* cnt    = rowptr + 40064;         // 40000 (padded 40064): hist counts, then fill cursor
    int* esrc   = cnt + 40064;            // 680000 edge sources, CSR-ordered by dst
    float* h1    = (float*)(esrc + 680000);  // 40000*128
    float* asrc1 = h1 + 5120000;             // 40000*4
    float* adst1 = asrc1 + 160000;           // 40000*4
    float* agg1  = adst1 + 160000;           // 40000*128
    // after gather1, h1 region is dead -> reuse for layer-2 buffers
    float* h2    = h1;                       // 40000*32
    float* asrc2 = h1 + 1280000;             // 40000
    float* adst2 = asrc2 + 40000;            // 40000
    float* agg2  = adst2 + 40000;            // 40000*32

    hipMemsetAsync(cnt, 0, 40000 * sizeof(int), stream);

    // CSR build (shared by both layers)
    hist_kernel<<<(E_TOT + 255) / 256, 256, 0, stream>>>(eidx, cnt);
    scan_kernel<<<1, 1024, 0, stream>>>(cnt, rowptr);
    fill_kernel<<<(E_TOT + 255) / 256, 256, 0, stream>>>(eidx, rowptr, cnt, esrc);

    // Layer 1
    gemm1_kernel<<<625, 256, 0, stream>>>(x, W1, a_src1, a_dst1, h1, asrc1, adst1);
    gather1_kernel<<<10000, 256, 0, stream>>>(rowptr, esrc, asrc1, adst1, h1, b1, agg1);

    // Layer 2
    gemm2_kernel<<<625, 256, 0, stream>>>(agg1, W2, a_src2, a_dst2, h2, asrc2, adst2);
    gather2_kernel<<<5000, 256, 0, stream>>>(rowptr, esrc, asrc2, adst2, h2, b2, agg2);

    // Output projection
    out_gemm_kernel<<<1250, 256, 0, stream>>>(agg2, W_out, b_out, out);
}

// Round 3
// 237.803 us; speedup vs baseline: 3.2563x; 1.3159x over previous
//
#include <hip/hip_runtime.h>

#define N_NODES 40000
#define E_EDGES 640000
#define E_TOT   (E_EDGES + N_NODES)

typedef unsigned int uint;
typedef unsigned short ushort;

// bf16 helpers (RNE pack, cheap unpack)
__device__ __forceinline__ ushort f2bf(float f) {
    uint u = __float_as_uint(f);
    u += 0x7FFFu + ((u >> 16) & 1u);
    return (ushort)(u >> 16);
}
__device__ __forceinline__ uint pk_bf(float lo, float hi) {
    return (uint)f2bf(lo) | ((uint)f2bf(hi) << 16);
}
__device__ __forceinline__ float bf_lo(uint w) { return __uint_as_float(w << 16); }
__device__ __forceinline__ float bf_hi(uint w) { return __uint_as_float(w & 0xFFFF0000u); }

// ===========================================================================
// CSR build: histogram -> single-block shuffle scan -> fill.
// ===========================================================================
__global__ __launch_bounds__(256) void hist_kernel(
    const int* __restrict__ eidx, int* __restrict__ cnt)
{
    const int e = blockIdx.x * 256 + threadIdx.x;
    if (e >= E_TOT) return;
    const int d = (e < E_EDGES) ? eidx[E_EDGES + e] : e - E_EDGES;
    atomicAdd(&cnt[d], 1);
}

// One block, 1024 threads, each owns 40 consecutive nodes. Register-serial
// prefix + wave shuffle scan + cross-wave LDS scan. Zeroes cnt for reuse.
__global__ __launch_bounds__(1024) void scan_kernel(
    int* __restrict__ cnt, int* __restrict__ rowptr)
{
    const int t = threadIdx.x;
    const int lane = t & 63;
    const int wave = t >> 6;
    const int base_i = t * 40;

    int v[40];
    int sum = 0;
#pragma unroll
    for (int j = 0; j < 40; ++j) {
        const int i = base_i + j;
        const int c = (i < N_NODES) ? cnt[i] : 0;
        v[j] = sum;          // exclusive prefix within thread
        sum += c;
    }

    // inclusive scan of per-thread sums within the wave
    int incl = sum;
#pragma unroll
    for (int off = 1; off < 64; off <<= 1) {
        int u = __shfl_up(incl, off);
        if (lane >= off) incl += u;
    }

    __shared__ int wsum[16];
    __shared__ int wbase[16];
    __shared__ int total;
    if (lane == 63) wsum[wave] = incl;
    __syncthreads();
    if (t < 16) {
        int w = wsum[t];
        int iw = w;
#pragma unroll
        for (int off = 1; off < 16; off <<= 1) {
            int u = __shfl_up(iw, off);
            if (t >= off) iw += u;
        }
        wbase[t] = iw - w;   // exclusive
        if (t == 15) total = iw;
    }
    __syncthreads();

    const int tbase = wbase[wave] + (incl - sum);
#pragma unroll
    for (int j = 0; j < 40; ++j) {
        const int i = base_i + j;
        if (i < N_NODES) { rowptr[i] = tbase + v[j]; cnt[i] = 0; }
    }
    if (t == 0) rowptr[N_NODES] = total;
}

__global__ __launch_bounds__(256) void fill_kernel(
    const int* __restrict__ eidx, const int* __restrict__ rowptr,
    int* __restrict__ cursor, int* __restrict__ esrc)
{
    const int e = blockIdx.x * 256 + threadIdx.x;
    if (e >= E_TOT) return;
    int s, d;
    if (e < E_EDGES) { s = eidx[e]; d = eidx[E_EDGES + e]; }
    else             { s = d = e - E_EDGES; }
    const int pos = atomicAdd(&cursor[d], 1);
    esrc[rowptr[d] + pos] = s;
}

// ===========================================================================
// GEMM1: h1 = x @ W1  [40000x128 @ 128x128]; h1 stored as bf16 for the gather;
// attention coeffs computed from f32 accumulators (full precision).
// ===========================================================================
__global__ __launch_bounds__(256) void gemm1_kernel(
    const float* __restrict__ x, const float* __restrict__ W,
    const float* __restrict__ a_src, const float* __restrict__ a_dst,
    ushort* __restrict__ h1b, float* __restrict__ asrc, float* __restrict__ adst)
{
    __shared__ float Ws[128 * 128];   // 64 KB
    {
        const float4* Wg = (const float4*)W;
        float4* Wl = (float4*)Ws;
        for (int i = threadIdx.x; i < 128 * 128 / 4; i += 256) Wl[i] = Wg[i];
    }
    __syncthreads();
    const int row0 = blockIdx.x * 64;
    const int tx = threadIdx.x & 15;   // 16 col-groups of 8 cols
    const int ty = threadIdx.x >> 4;   // 16 row-groups of 4 rows

    float acc[4][8];
#pragma unroll
    for (int r = 0; r < 4; ++r)
#pragma unroll
        for (int c = 0; c < 8; ++c) acc[r][c] = 0.f;

    for (int k0 = 0; k0 < 128; k0 += 4) {
        float xv[4][4];
#pragma unroll
        for (int r = 0; r < 4; ++r) {
            float4 t = *(const float4*)&x[(size_t)(row0 + ty * 4 + r) * 128 + k0];
            xv[r][0] = t.x; xv[r][1] = t.y; xv[r][2] = t.z; xv[r][3] = t.w;
        }
#pragma unroll
        for (int kk = 0; kk < 4; ++kk) {
            float wreg[8];
            float4 w0 = *(const float4*)&Ws[(k0 + kk) * 128 + tx * 8];
            float4 w1 = *(const float4*)&Ws[(k0 + kk) * 128 + tx * 8 + 4];
            wreg[0] = w0.x; wreg[1] = w0.y; wreg[2] = w0.z; wreg[3] = w0.w;
            wreg[4] = w1.x; wreg[5] = w1.y; wreg[6] = w1.z; wreg[7] = w1.w;
#pragma unroll
            for (int r = 0; r < 4; ++r)
#pragma unroll
                for (int c = 0; c < 8; ++c)
                    acc[r][c] = fmaf(xv[r][kk], wreg[c], acc[r][c]);
        }
    }

    const int head  = tx >> 2;
    const int cbase = (tx & 3) * 8;
    float as[8], ad[8];
#pragma unroll
    for (int c = 0; c < 8; ++c) {
        as[c] = a_src[head * 32 + cbase + c];
        ad[c] = a_dst[head * 32 + cbase + c];
    }
#pragma unroll
    for (int r = 0; r < 4; ++r) {
        const int n = row0 + ty * 4 + r;
        uint4 o;
        o.x = pk_bf(acc[r][0], acc[r][1]);
        o.y = pk_bf(acc[r][2], acc[r][3]);
        o.z = pk_bf(acc[r][4], acc[r][5]);
        o.w = pk_bf(acc[r][6], acc[r][7]);
        *(uint4*)&h1b[(size_t)n * 128 + tx * 8] = o;
        float ps = 0.f, pd = 0.f;
#pragma unroll
        for (int c = 0; c < 8; ++c) {
            ps = fmaf(acc[r][c], as[c], ps);
            pd = fmaf(acc[r][c], ad[c], pd);
        }
        ps += __shfl_xor(ps, 1); ps += __shfl_xor(ps, 2);
        pd += __shfl_xor(pd, 1); pd += __shfl_xor(pd, 2);
        if ((threadIdx.x & 3) == 0) {
            asrc[n * 4 + head] = ps;
            adst[n * 4 + head] = pd;
        }
    }
}

// ===========================================================================
// Gather pass 1: one wave per dst node, bf16 h1 rows (256 B), 4-deep manual
// memory pipeline; fused normalize + bias + ELU.
// ===========================================================================
__global__ __launch_bounds__(256) void gather1_kernel(
    const int* __restrict__ rowptr, const int* __restrict__ esrc,
    const float* __restrict__ asrc, const float* __restrict__ adst,
    const ushort* __restrict__ h1b, const float* __restrict__ b,
    float* __restrict__ agg)
{
    const int node = (blockIdx.x * 256 + threadIdx.x) >> 6;
    const int lane = threadIdx.x & 63;
    if (node >= N_NODES) return;
    const int head = lane >> 4;
    const float ad = adst[node * 4 + head];
    const int beg = rowptr[node], end = rowptr[node + 1];
    float acc0 = 0.f, acc1 = 0.f, den = 0.f;

    int i = beg;
    for (; i + 4 <= end; i += 4) {
        const int s0 = esrc[i], s1 = esrc[i + 1], s2 = esrc[i + 2], s3 = esrc[i + 3];
        const float a0 = asrc[s0 * 4 + head];
        const float a1 = asrc[s1 * 4 + head];
        const float a2 = asrc[s2 * 4 + head];
        const float a3 = asrc[s3 * 4 + head];
        const uint w0 = *(const uint*)&h1b[(size_t)s0 * 128 + lane * 2];
        const uint w1 = *(const uint*)&h1b[(size_t)s1 * 128 + lane * 2];
        const uint w2 = *(const uint*)&h1b[(size_t)s2 * 128 + lane * 2];
        const uint w3 = *(const uint*)&h1b[(size_t)s3 * 128 + lane * 2];
        float v0 = a0 + ad; v0 = v0 > 0.f ? v0 : 0.2f * v0;
        float v1 = a1 + ad; v1 = v1 > 0.f ? v1 : 0.2f * v1;
        float v2 = a2 + ad; v2 = v2 > 0.f ? v2 : 0.2f * v2;
        float v3 = a3 + ad; v3 = v3 > 0.f ? v3 : 0.2f * v3;
        const float e0 = __expf(v0), e1 = __expf(v1), e2 = __expf(v2), e3 = __expf(v3);
        den += (e0 + e1) + (e2 + e3);
        acc0 = fmaf(e0, bf_lo(w0), acc0); acc1 = fmaf(e0, bf_hi(w0), acc1);
        acc0 = fmaf(e1, bf_lo(w1), acc0); acc1 = fmaf(e1, bf_hi(w1), acc1);
        acc0 = fmaf(e2, bf_lo(w2), acc0); acc1 = fmaf(e2, bf_hi(w2), acc1);
        acc0 = fmaf(e3, bf_lo(w3), acc0); acc1 = fmaf(e3, bf_hi(w3), acc1);
    }
    for (; i < end; ++i) {
        const int s = esrc[i];
        float av = asrc[s * 4 + head] + ad;
        av = av > 0.f ? av : 0.2f * av;
        const float ex = __expf(av);
        const uint w = *(const uint*)&h1b[(size_t)s * 128 + lane * 2];
        den += ex;
        acc0 = fmaf(ex, bf_lo(w), acc0);
        acc1 = fmaf(ex, bf_hi(w), acc1);
    }

    const float inv = 1.f / (den + 1e-16f);
    const float2 bv = *(const float2*)&b[lane * 2];
    float o0 = acc0 * inv + bv.x;
    float o1 = acc1 * inv + bv.y;
    o0 = o0 > 0.f ? o0 : expm1f(o0);
    o1 = o1 > 0.f ? o1 : expm1f(o1);
    *(float2*)&agg[(size_t)node * 128 + lane * 2] = make_float2(o0, o1);
}

// ===========================================================================
// GEMM2: h2 = hin @ W2  [40000x128 @ 128x32], fused attention coeffs (1 head)
// ===========================================================================
__global__ __launch_bounds__(256) void gemm2_kernel(
    const float* __restrict__ hin, const float* __restrict__ W,
    const float* __restrict__ a_src, const float* __restrict__ a_dst,
    float* __restrict__ h2, float* __restrict__ asrc, float* __restrict__ adst)
{
    __shared__ float Ws[128 * 32];   // 16 KB
    {
        const float4* Wg = (const float4*)W;
        float4* Wl = (float4*)Ws;
        for (int i = threadIdx.x; i < 128 * 32 / 4; i += 256) Wl[i] = Wg[i];
    }
    __syncthreads();
    const int row0 = blockIdx.x * 64;
    const int tx = threadIdx.x & 7;
    const int ty = threadIdx.x >> 3;

    float acc[2][4];
#pragma unroll
    for (int r = 0; r < 2; ++r)
#pragma unroll
        for (int c = 0; c < 4; ++c) acc[r][c] = 0.f;

    for (int k0 = 0; k0 < 128; k0 += 4) {
        float xv[2][4];
#pragma unroll
        for (int r = 0; r < 2; ++r) {
            float4 t = *(const float4*)&hin[(size_t)(row0 + ty * 2 + r) * 128 + k0];
            xv[r][0] = t.x; xv[r][1] = t.y; xv[r][2] = t.z; xv[r][3] = t.w;
        }
#pragma unroll
        for (int kk = 0; kk < 4; ++kk) {
            float4 w = *(const float4*)&Ws[(k0 + kk) * 32 + tx * 4];
            float wreg[4] = { w.x, w.y, w.z, w.w };
#pragma unroll
            for (int r = 0; r < 2; ++r)
#pragma unroll
                for (int c = 0; c < 4; ++c)
                    acc[r][c] = fmaf(xv[r][kk], wreg[c], acc[r][c]);
        }
    }

    float as[4], ad[4];
#pragma unroll
    for (int c = 0; c < 4; ++c) {
        as[c] = a_src[tx * 4 + c];
        ad[c] = a_dst[tx * 4 + c];
    }
#pragma unroll
    for (int r = 0; r < 2; ++r) {
        const int n = row0 + ty * 2 + r;
        *(float4*)&h2[(size_t)n * 32 + tx * 4] =
            make_float4(acc[r][0], acc[r][1], acc[r][2], acc[r][3]);
        float ps = 0.f, pd = 0.f;
#pragma unroll
        for (int c = 0; c < 4; ++c) {
            ps = fmaf(acc[r][c], as[c], ps);
            pd = fmaf(acc[r][c], ad[c], pd);
        }
        ps += __shfl_xor(ps, 1); ps += __shfl_xor(ps, 2); ps += __shfl_xor(ps, 4);
        pd += __shfl_xor(pd, 1); pd += __shfl_xor(pd, 2); pd += __shfl_xor(pd, 4);
        if ((threadIdx.x & 7) == 0) { asrc[n] = ps; adst[n] = pd; }
    }
}

// ===========================================================================
// Gather pass 2: 32 lanes per dst node, 4-deep pipeline; fused norm+bias+ELU.
// ===========================================================================
__global__ __launch_bounds__(256) void gather2_kernel(
    const int* __restrict__ rowptr, const int* __restrict__ esrc,
    const float* __restrict__ asrc, const float* __restrict__ adst,
    const float* __restrict__ h2, const float* __restrict__ b,
    float* __restrict__ agg)
{
    const int t = blockIdx.x * 256 + threadIdx.x;
    const int node = t >> 5;
    const int c = t & 31;
    if (node >= N_NODES) return;
    const float ad = adst[node];
    const int beg = rowptr[node], end = rowptr[node + 1];
    float acc = 0.f, den = 0.f;

    int i = beg;
    for (; i + 4 <= end; i += 4) {
        const int s0 = esrc[i], s1 = esrc[i + 1], s2 = esrc[i + 2], s3 = esrc[i + 3];
        const float a0 = asrc[s0], a1 = asrc[s1], a2 = asrc[s2], a3 = asrc[s3];
        const float h0 = h2[(size_t)s0 * 32 + c];
        const float h1 = h2[(size_t)s1 * 32 + c];
        const float hh2 = h2[(size_t)s2 * 32 + c];
        const float h3 = h2[(size_t)s3 * 32 + c];
        float v0 = a0 + ad; v0 = v0 > 0.f ? v0 : 0.2f * v0;
        float v1 = a1 + ad; v1 = v1 > 0.f ? v1 : 0.2f * v1;
        float v2 = a2 + ad; v2 = v2 > 0.f ? v2 : 0.2f * v2;
        float v3 = a3 + ad; v3 = v3 > 0.f ? v3 : 0.2f * v3;
        const float e0 = __expf(v0), e1 = __expf(v1), e2 = __expf(v2), e3 = __expf(v3);
        den += (e0 + e1) + (e2 + e3);
        acc = fmaf(e0, h0, acc);
        acc = fmaf(e1, h1, acc);
        acc = fmaf(e2, hh2, acc);
        acc = fmaf(e3, h3, acc);
    }
    for (; i < end; ++i) {
        const int s = esrc[i];
        float av = asrc[s] + ad;
        av = av > 0.f ? av : 0.2f * av;
        const float ex = __expf(av);
        den += ex;
        acc = fmaf(ex, h2[(size_t)s * 32 + c], acc);
    }

    const float inv = 1.f / (den + 1e-16f);
    float o = acc * inv + b[c];
    o = o > 0.f ? o : expm1f(o);
    agg[(size_t)node * 32 + c] = o;
}

// ===========================================================================
// Output GEMM: out = h3 @ W_out + b_out  [40000x32 @ 32x112]
// ===========================================================================
__global__ __launch_bounds__(256) void out_gemm_kernel(
    const float* __restrict__ h3, const float* __restrict__ W,
    const float* __restrict__ b, float* __restrict__ out)
{
    __shared__ float Ws[32 * 112];   // 14 KB
    {
        const float4* Wg = (const float4*)W;
        float4* Wl = (float4*)Ws;
        for (int i = threadIdx.x; i < 32 * 112 / 4; i += 256) Wl[i] = Wg[i];
    }
    __syncthreads();
    const int row0 = blockIdx.x * 32;
    const int tc = threadIdx.x & 15;
    const int tr = threadIdx.x >> 4;

    float acc[2][7];
#pragma unroll
    for (int r = 0; r < 2; ++r)
#pragma unroll
        for (int c = 0; c < 7; ++c) acc[r][c] = 0.f;

    for (int k0 = 0; k0 < 32; k0 += 4) {
        float xv[2][4];
#pragma unroll
        for (int r = 0; r < 2; ++r) {
            float4 t = *(const float4*)&h3[(size_t)(row0 + tr * 2 + r) * 32 + k0];
            xv[r][0] = t.x; xv[r][1] = t.y; xv[r][2] = t.z; xv[r][3] = t.w;
        }
#pragma unroll
        for (int kk = 0; kk < 4; ++kk) {
            float wv[7];
#pragma unroll
            for (int c = 0; c < 7; ++c) wv[c] = Ws[(k0 + kk) * 112 + tc * 7 + c];
#pragma unroll
            for (int r = 0; r < 2; ++r)
#pragma unroll
                for (int c = 0; c < 7; ++c)
                    acc[r][c] = fmaf(xv[r][kk], wv[c], acc[r][c]);
        }
    }
#pragma unroll
    for (int r = 0; r < 2; ++r) {
        const int n = row0 + tr * 2 + r;
#pragma unroll
        for (int c = 0; c < 7; ++c)
            out[(size_t)n * 112 + tc * 7 + c] = acc[r][c] + b[tc * 7 + c];
    }
}

// ===========================================================================
extern "C" void kernel_launch(void* const* d_in, const int* in_sizes, int n_in,
                              void* d_out, int out_size, void* d_ws, size_t ws_size,
                              hipStream_t stream) {
    const float* x      = (const float*)d_in[0];
    const int*   eidx   = (const int*)d_in[1];
    const float* W1     = (const float*)d_in[2];
    const float* a_src1 = (const float*)d_in[3];
    const float* a_dst1 = (const float*)d_in[4];
    const float* b1     = (const float*)d_in[5];
    const float* W2     = (const float*)d_in[6];
    const float* a_src2 = (const float*)d_in[7];
    const float* a_dst2 = (const float*)d_in[8];
    const float* b2     = (const float*)d_in[9];
    const float* W_out  = (const float*)d_in[10];
    const float* b_out  = (const float*)d_in[11];
    float* out = (float*)d_out;

    // ---- workspace layout (~35 MB) ----
    int* rowptr = (int*)d_ws;                // 40064
    int* cnt    = rowptr + 40064;            // 40064 (hist counts, then fill cursor)
    int* esrc   = cnt + 40064;               // 680000 CSR edge sources
    ushort* h1b  = (ushort*)(esrc + 680000); // 40000*128 bf16 (2,560,000 floats worth)
    float* asrc1 = (float*)(h1b + 5120000);  // 40000*4
    float* adst1 = asrc1 + 160000;           // 40000*4
    float* agg1  = adst1 + 160000;           // 40000*128
    // after gather1, h1b+asrc1+adst1 region (2.88M floats) is dead -> layer 2
    float* h2    = (float*)h1b;              // 40000*32
    float* asrc2 = h2 + 1280000;             // 40000
    float* adst2 = asrc2 + 40000;            // 40000
    float* agg2  = adst2 + 40000;            // 40000*32 (ends at 2.64M < 2.88M)

    hipMemsetAsync(cnt, 0, 40000 * sizeof(int), stream);

    // CSR build (shared by both layers)
    hist_kernel<<<(E_TOT + 255) / 256, 256, 0, stream>>>(eidx, cnt);
    scan_kernel<<<1, 1024, 0, stream>>>(cnt, rowptr);
    fill_kernel<<<(E_TOT + 255) / 256, 256, 0, stream>>>(eidx, rowptr, cnt, esrc);

    // Layer 1
    gemm1_kernel<<<625, 256, 0, stream>>>(x, W1, a_src1, a_dst1, h1b, asrc1, adst1);
    gather1_kernel<<<10000, 256, 0, stream>>>(rowptr, esrc, asrc1, adst1, h1b, b1, agg1);

    // Layer 2
    gemm2_kernel<<<625, 256, 0, stream>>>(agg1, W2, a_src2, a_dst2, h2, asrc2, adst2);
    gather2_kernel<<<5000, 256, 0, stream>>>(rowptr, esrc, asrc2, adst2, h2, b2, agg2);

    // Output projection
    out_gemm_kernel<<<1250, 256, 0, stream>>>(agg2, W_out, b_out, out);
}

// Round 4
// 183.953 us; speedup vs baseline: 4.2096x; 1.2927x over previous
//
#include <hip/hip_runtime.h>

#define N_NODES 40000
#define E_EDGES 640000
#define E_TOT   (E_EDGES + N_NODES)
#define SCAN_BLOCKS ((N_NODES + 255) / 256)   // 157

typedef unsigned int uint;
typedef unsigned short ushort;

// bf16 helpers (RNE pack, cheap unpack)
__device__ __forceinline__ ushort f2bf(float f) {
    uint u = __float_as_uint(f);
    u += 0x7FFFu + ((u >> 16) & 1u);
    return (ushort)(u >> 16);
}
__device__ __forceinline__ uint pk_bf(float lo, float hi) {
    return (uint)f2bf(lo) | ((uint)f2bf(hi) << 16);
}
__device__ __forceinline__ float bf_lo(uint w) { return __uint_as_float(w << 16); }
__device__ __forceinline__ float bf_hi(uint w) { return __uint_as_float(w & 0xFFFF0000u); }

// ===========================================================================
// CSR build: histogram -> 3-kernel hierarchical scan -> fill.
// ===========================================================================
__global__ __launch_bounds__(256) void hist_kernel(
    const int* __restrict__ eidx, int* __restrict__ cnt)
{
    const int e = blockIdx.x * 256 + threadIdx.x;
    if (e >= E_TOT) return;
    const int d = (e < E_EDGES) ? eidx[E_EDGES + e] : e - E_EDGES;
    atomicAdd(&cnt[d], 1);
}

// Block-local exclusive scan of 256 contiguous elements; block total -> bsum.
__global__ __launch_bounds__(256) void scanA_kernel(
    const int* __restrict__ cnt, int* __restrict__ rowptr, int* __restrict__ bsum)
{
    const int i = blockIdx.x * 256 + threadIdx.x;
    const int lane = threadIdx.x & 63;
    const int wave = threadIdx.x >> 6;
    const int v = (i < N_NODES) ? cnt[i] : 0;
    int incl = v;
#pragma unroll
    for (int off = 1; off < 64; off <<= 1) {
        int u = __shfl_up(incl, off);
        if (lane >= off) incl += u;
    }
    __shared__ int ws[4];
    if (lane == 63) ws[wave] = incl;
    __syncthreads();
    int woff = 0;
    if (wave > 0) woff += ws[0];
    if (wave > 1) woff += ws[1];
    if (wave > 2) woff += ws[2];
    if (i < N_NODES) rowptr[i] = woff + incl - v;   // block-local exclusive
    if (threadIdx.x == 255) bsum[blockIdx.x] = woff + incl;
}

// Single block: exclusive scan of the block sums; write grand total.
__global__ __launch_bounds__(256) void scanB_kernel(
    int* __restrict__ bsum, int* __restrict__ rowptr)
{
    const int t = threadIdx.x;
    const int lane = t & 63;
    const int wave = t >> 6;
    const int v = (t < SCAN_BLOCKS) ? bsum[t] : 0;
    int incl = v;
#pragma unroll
    for (int off = 1; off < 64; off <<= 1) {
        int u = __shfl_up(incl, off);
        if (lane >= off) incl += u;
    }
    __shared__ int ws[4];
    if (lane == 63) ws[wave] = incl;
    __syncthreads();
    int woff = 0;
    if (wave > 0) woff += ws[0];
    if (wave > 1) woff += ws[1];
    if (wave > 2) woff += ws[2];
    if (t < SCAN_BLOCKS) bsum[t] = woff + incl - v;  // exclusive
    if (t == 255) rowptr[N_NODES] = woff + incl;     // grand total (v=0 here)
}

// Add block offsets; zero cnt for reuse as the fill cursor.
__global__ __launch_bounds__(256) void scanC_kernel(
    int* __restrict__ rowptr, const int* __restrict__ bsum, int* __restrict__ cnt)
{
    const int i = blockIdx.x * 256 + threadIdx.x;
    if (i >= N_NODES) return;
    rowptr[i] += bsum[blockIdx.x];
    cnt[i] = 0;
}

__global__ __launch_bounds__(256) void fill_kernel(
    const int* __restrict__ eidx, const int* __restrict__ rowptr,
    int* __restrict__ cursor, int* __restrict__ esrc)
{
    const int e = blockIdx.x * 256 + threadIdx.x;
    if (e >= E_TOT) return;
    int s, d;
    if (e < E_EDGES) { s = eidx[e]; d = eidx[E_EDGES + e]; }
    else             { s = d = e - E_EDGES; }
    const int pos = atomicAdd(&cursor[d], 1);
    esrc[rowptr[d] + pos] = s;
}

// ===========================================================================
// GEMM1: h1 = x @ W1  [40000x128 @ 128x128]; h1 stored as bf16 for the gather;
// attention coeffs computed from f32 accumulators (full precision).
// ===========================================================================
__global__ __launch_bounds__(256) void gemm1_kernel(
    const float* __restrict__ x, const float* __restrict__ W,
    const float* __restrict__ a_src, const float* __restrict__ a_dst,
    ushort* __restrict__ h1b, float* __restrict__ asrc, float* __restrict__ adst)
{
    __shared__ float Ws[128 * 128];   // 64 KB
    {
        const float4* Wg = (const float4*)W;
        float4* Wl = (float4*)Ws;
        for (int i = threadIdx.x; i < 128 * 128 / 4; i += 256) Wl[i] = Wg[i];
    }
    __syncthreads();
    const int row0 = blockIdx.x * 64;
    const int tx = threadIdx.x & 15;   // 16 col-groups of 8 cols
    const int ty = threadIdx.x >> 4;   // 16 row-groups of 4 rows

    float acc[4][8];
#pragma unroll
    for (int r = 0; r < 4; ++r)
#pragma unroll
        for (int c = 0; c < 8; ++c) acc[r][c] = 0.f;

    for (int k0 = 0; k0 < 128; k0 += 4) {
        float xv[4][4];
#pragma unroll
        for (int r = 0; r < 4; ++r) {
            float4 t = *(const float4*)&x[(size_t)(row0 + ty * 4 + r) * 128 + k0];
            xv[r][0] = t.x; xv[r][1] = t.y; xv[r][2] = t.z; xv[r][3] = t.w;
        }
#pragma unroll
        for (int kk = 0; kk < 4; ++kk) {
            float wreg[8];
            float4 w0 = *(const float4*)&Ws[(k0 + kk) * 128 + tx * 8];
            float4 w1 = *(const float4*)&Ws[(k0 + kk) * 128 + tx * 8 + 4];
            wreg[0] = w0.x; wreg[1] = w0.y; wreg[2] = w0.z; wreg[3] = w0.w;
            wreg[4] = w1.x; wreg[5] = w1.y; wreg[6] = w1.z; wreg[7] = w1.w;
#pragma unroll
            for (int r = 0; r < 4; ++r)
#pragma unroll
                for (int c = 0; c < 8; ++c)
                    acc[r][c] = fmaf(xv[r][kk], wreg[c], acc[r][c]);
        }
    }

    const int head  = tx >> 2;
    const int cbase = (tx & 3) * 8;
    float as[8], ad[8];
#pragma unroll
    for (int c = 0; c < 8; ++c) {
        as[c] = a_src[head * 32 + cbase + c];
        ad[c] = a_dst[head * 32 + cbase + c];
    }
#pragma unroll
    for (int r = 0; r < 4; ++r) {
        const int n = row0 + ty * 4 + r;
        uint4 o;
        o.x = pk_bf(acc[r][0], acc[r][1]);
        o.y = pk_bf(acc[r][2], acc[r][3]);
        o.z = pk_bf(acc[r][4], acc[r][5]);
        o.w = pk_bf(acc[r][6], acc[r][7]);
        *(uint4*)&h1b[(size_t)n * 128 + tx * 8] = o;
        float ps = 0.f, pd = 0.f;
#pragma unroll
        for (int c = 0; c < 8; ++c) {
            ps = fmaf(acc[r][c], as[c], ps);
            pd = fmaf(acc[r][c], ad[c], pd);
        }
        ps += __shfl_xor(ps, 1); ps += __shfl_xor(ps, 2);
        pd += __shfl_xor(pd, 1); pd += __shfl_xor(pd, 2);
        if ((threadIdx.x & 3) == 0) {
            asrc[n * 4 + head] = ps;
            adst[n * 4 + head] = pd;
        }
    }
}

// ===========================================================================
// Gather pass 1: one wave per dst node, bf16 h1 rows (256 B), 4-deep manual
// memory pipeline; fused normalize + bias + ELU.
// ===========================================================================
__global__ __launch_bounds__(256) void gather1_kernel(
    const int* __restrict__ rowptr, const int* __restrict__ esrc,
    const float* __restrict__ asrc, const float* __restrict__ adst,
    const ushort* __restrict__ h1b, const float* __restrict__ b,
    float* __restrict__ agg)
{
    const int node = (blockIdx.x * 256 + threadIdx.x) >> 6;
    const int lane = threadIdx.x & 63;
    if (node >= N_NODES) return;
    const int head = lane >> 4;
    const float ad = adst[node * 4 + head];
    const int beg = rowptr[node], end = rowptr[node + 1];
    float acc0 = 0.f, acc1 = 0.f, den = 0.f;

    int i = beg;
    for (; i + 4 <= end; i += 4) {
        const int s0 = esrc[i], s1 = esrc[i + 1], s2 = esrc[i + 2], s3 = esrc[i + 3];
        const float a0 = asrc[s0 * 4 + head];
        const float a1 = asrc[s1 * 4 + head];
        const float a2 = asrc[s2 * 4 + head];
        const float a3 = asrc[s3 * 4 + head];
        const uint w0 = *(const uint*)&h1b[(size_t)s0 * 128 + lane * 2];
        const uint w1 = *(const uint*)&h1b[(size_t)s1 * 128 + lane * 2];
        const uint w2 = *(const uint*)&h1b[(size_t)s2 * 128 + lane * 2];
        const uint w3 = *(const uint*)&h1b[(size_t)s3 * 128 + lane * 2];
        float v0 = a0 + ad; v0 = v0 > 0.f ? v0 : 0.2f * v0;
        float v1 = a1 + ad; v1 = v1 > 0.f ? v1 : 0.2f * v1;
        float v2 = a2 + ad; v2 = v2 > 0.f ? v2 : 0.2f * v2;
        float v3 = a3 + ad; v3 = v3 > 0.f ? v3 : 0.2f * v3;
        const float e0 = __expf(v0), e1 = __expf(v1), e2 = __expf(v2), e3 = __expf(v3);
        den += (e0 + e1) + (e2 + e3);
        acc0 = fmaf(e0, bf_lo(w0), acc0); acc1 = fmaf(e0, bf_hi(w0), acc1);
        acc0 = fmaf(e1, bf_lo(w1), acc0); acc1 = fmaf(e1, bf_hi(w1), acc1);
        acc0 = fmaf(e2, bf_lo(w2), acc0); acc1 = fmaf(e2, bf_hi(w2), acc1);
        acc0 = fmaf(e3, bf_lo(w3), acc0); acc1 = fmaf(e3, bf_hi(w3), acc1);
    }
    for (; i < end; ++i) {
        const int s = esrc[i];
        float av = asrc[s * 4 + head] + ad;
        av = av > 0.f ? av : 0.2f * av;
        const float ex = __expf(av);
        const uint w = *(const uint*)&h1b[(size_t)s * 128 + lane * 2];
        den += ex;
        acc0 = fmaf(ex, bf_lo(w), acc0);
        acc1 = fmaf(ex, bf_hi(w), acc1);
    }

    const float inv = 1.f / (den + 1e-16f);
    const float2 bv = *(const float2*)&b[lane * 2];
    float o0 = acc0 * inv + bv.x;
    float o1 = acc1 * inv + bv.y;
    o0 = o0 > 0.f ? o0 : expm1f(o0);
    o1 = o1 > 0.f ? o1 : expm1f(o1);
    *(float2*)&agg[(size_t)node * 128 + lane * 2] = make_float2(o0, o1);
}

// ===========================================================================
// GEMM2: h2 = hin @ W2  [40000x128 @ 128x32], fused attention coeffs (1 head)
// ===========================================================================
__global__ __launch_bounds__(256) void gemm2_kernel(
    const float* __restrict__ hin, const float* __restrict__ W,
    const float* __restrict__ a_src, const float* __restrict__ a_dst,
    float* __restrict__ h2, float* __restrict__ asrc, float* __restrict__ adst)
{
    __shared__ float Ws[128 * 32];   // 16 KB
    {
        const float4* Wg = (const float4*)W;
        float4* Wl = (float4*)Ws;
        for (int i = threadIdx.x; i < 128 * 32 / 4; i += 256) Wl[i] = Wg[i];
    }
    __syncthreads();
    const int row0 = blockIdx.x * 64;
    const int tx = threadIdx.x & 7;
    const int ty = threadIdx.x >> 3;

    float acc[2][4];
#pragma unroll
    for (int r = 0; r < 2; ++r)
#pragma unroll
        for (int c = 0; c < 4; ++c) acc[r][c] = 0.f;

    for (int k0 = 0; k0 < 128; k0 += 4) {
        float xv[2][4];
#pragma unroll
        for (int r = 0; r < 2; ++r) {
            float4 t = *(const float4*)&hin[(size_t)(row0 + ty * 2 + r) * 128 + k0];
            xv[r][0] = t.x; xv[r][1] = t.y; xv[r][2] = t.z; xv[r][3] = t.w;
        }
#pragma unroll
        for (int kk = 0; kk < 4; ++kk) {
            float4 w = *(const float4*)&Ws[(k0 + kk) * 32 + tx * 4];
            float wreg[4] = { w.x, w.y, w.z, w.w };
#pragma unroll
            for (int r = 0; r < 2; ++r)
#pragma unroll
                for (int c = 0; c < 4; ++c)
                    acc[r][c] = fmaf(xv[r][kk], wreg[c], acc[r][c]);
        }
    }

    float as[4], ad[4];
#pragma unroll
    for (int c = 0; c < 4; ++c) {
        as[c] = a_src[tx * 4 + c];
        ad[c] = a_dst[tx * 4 + c];
    }
#pragma unroll
    for (int r = 0; r < 2; ++r) {
        const int n = row0 + ty * 2 + r;
        *(float4*)&h2[(size_t)n * 32 + tx * 4] =
            make_float4(acc[r][0], acc[r][1], acc[r][2], acc[r][3]);
        float ps = 0.f, pd = 0.f;
#pragma unroll
        for (int c = 0; c < 4; ++c) {
            ps = fmaf(acc[r][c], as[c], ps);
            pd = fmaf(acc[r][c], ad[c], pd);
        }
        ps += __shfl_xor(ps, 1); ps += __shfl_xor(ps, 2); ps += __shfl_xor(ps, 4);
        pd += __shfl_xor(pd, 1); pd += __shfl_xor(pd, 2); pd += __shfl_xor(pd, 4);
        if ((threadIdx.x & 7) == 0) { asrc[n] = ps; adst[n] = pd; }
    }
}

// ===========================================================================
// Gather pass 2: 32 lanes per dst node, 4-deep pipeline; fused norm+bias+ELU.
// ===========================================================================
__global__ __launch_bounds__(256) void gather2_kernel(
    const int* __restrict__ rowptr, const int* __restrict__ esrc,
    const float* __restrict__ asrc, const float* __restrict__ adst,
    const float* __restrict__ h2, const float* __restrict__ b,
    float* __restrict__ agg)
{
    const int t = blockIdx.x * 256 + threadIdx.x;
    const int node = t >> 5;
    const int c = t & 31;
    if (node >= N_NODES) return;
    const float ad = adst[node];
    const int beg = rowptr[node], end = rowptr[node + 1];
    float acc = 0.f, den = 0.f;

    int i = beg;
    for (; i + 4 <= end; i += 4) {
        const int s0 = esrc[i], s1 = esrc[i + 1], s2 = esrc[i + 2], s3 = esrc[i + 3];
        const float a0 = asrc[s0], a1 = asrc[s1], a2 = asrc[s2], a3 = asrc[s3];
        const float h0 = h2[(size_t)s0 * 32 + c];
        const float h1 = h2[(size_t)s1 * 32 + c];
        const float hh2 = h2[(size_t)s2 * 32 + c];
        const float h3 = h2[(size_t)s3 * 32 + c];
        float v0 = a0 + ad; v0 = v0 > 0.f ? v0 : 0.2f * v0;
        float v1 = a1 + ad; v1 = v1 > 0.f ? v1 : 0.2f * v1;
        float v2 = a2 + ad; v2 = v2 > 0.f ? v2 : 0.2f * v2;
        float v3 = a3 + ad; v3 = v3 > 0.f ? v3 : 0.2f * v3;
        const float e0 = __expf(v0), e1 = __expf(v1), e2 = __expf(v2), e3 = __expf(v3);
        den += (e0 + e1) + (e2 + e3);
        acc = fmaf(e0, h0, acc);
        acc = fmaf(e1, h1, acc);
        acc = fmaf(e2, hh2, acc);
        acc = fmaf(e3, h3, acc);
    }
    for (; i < end; ++i) {
        const int s = esrc[i];
        float av = asrc[s] + ad;
        av = av > 0.f ? av : 0.2f * av;
        const float ex = __expf(av);
        den += ex;
        acc = fmaf(ex, h2[(size_t)s * 32 + c], acc);
    }

    const float inv = 1.f / (den + 1e-16f);
    float o = acc * inv + b[c];
    o = o > 0.f ? o : expm1f(o);
    agg[(size_t)node * 32 + c] = o;
}

// ===========================================================================
// Output GEMM: out = h3 @ W_out + b_out  [40000x32 @ 32x112]
// ===========================================================================
__global__ __launch_bounds__(256) void out_gemm_kernel(
    const float* __restrict__ h3, const float* __restrict__ W,
    const float* __restrict__ b, float* __restrict__ out)
{
    __shared__ float Ws[32 * 112];   // 14 KB
    {
        const float4* Wg = (const float4*)W;
        float4* Wl = (float4*)Ws;
        for (int i = threadIdx.x; i < 32 * 112 / 4; i += 256) Wl[i] = Wg[i];
    }
    __syncthreads();
    const int row0 = blockIdx.x * 32;
    const int tc = threadIdx.x & 15;
    const int tr = threadIdx.x >> 4;

    float acc[2][7];
#pragma unroll
    for (int r = 0; r < 2; ++r)
#pragma unroll
        for (int c = 0; c < 7; ++c) acc[r][c] = 0.f;

    for (int k0 = 0; k0 < 32; k0 += 4) {
        float xv[2][4];
#pragma unroll
        for (int r = 0; r < 2; ++r) {
            float4 t = *(const float4*)&h3[(size_t)(row0 + tr * 2 + r) * 32 + k0];
            xv[r][0] = t.x; xv[r][1] = t.y; xv[r][2] = t.z; xv[r][3] = t.w;
        }
#pragma unroll
        for (int kk = 0; kk < 4; ++kk) {
            float wv[7];
#pragma unroll
            for (int c = 0; c < 7; ++c) wv[c] = Ws[(k0 + kk) * 112 + tc * 7 + c];
#pragma unroll
            for (int r = 0; r < 2; ++r)
#pragma unroll
                for (int c = 0; c < 7; ++c)
                    acc[r][c] = fmaf(xv[r][kk], wv[c], acc[r][c]);
        }
    }
#pragma unroll
    for (int r = 0; r < 2; ++r) {
        const int n = row0 + tr * 2 + r;
#pragma unroll
        for (int c = 0; c < 7; ++c)
            out[(size_t)n * 112 + tc * 7 + c] = acc[r][c] + b[tc * 7 + c];
    }
}

// ===========================================================================
extern "C" void kernel_launch(void* const* d_in, const int* in_sizes, int n_in,
                              void* d_out, int out_size, void* d_ws, size_t ws_size,
                              hipStream_t stream) {
    const float* x      = (const float*)d_in[0];
    const int*   eidx   = (const int*)d_in[1];
    const float* W1     = (const float*)d_in[2];
    const float* a_src1 = (const float*)d_in[3];
    const float* a_dst1 = (const float*)d_in[4];
    const float* b1     = (const float*)d_in[5];
    const float* W2     = (const float*)d_in[6];
    const float* a_src2 = (const float*)d_in[7];
    const float* a_dst2 = (const float*)d_in[8];
    const float* b2     = (const float*)d_in[9];
    const float* W_out  = (const float*)d_in[10];
    const float* b_out  = (const float*)d_in[11];
    float* out = (float*)d_out;

    // ---- workspace layout (~35 MB) ----
    int* rowptr = (int*)d_ws;                // 40064
    int* cnt    = rowptr + 40064;            // 40064 (hist counts, then fill cursor)
    int* bsum   = cnt + 40064;               // 192 (block sums for the scan)
    int* esrc   = bsum + 192;                // 680000 CSR edge sources
    ushort* h1b  = (ushort*)(esrc + 680000); // 40000*128 bf16
    float* asrc1 = (float*)(h1b + 5120000);  // 40000*4
    float* adst1 = asrc1 + 160000;           // 40000*4
    float* agg1  = adst1 + 160000;           // 40000*128
    // after gather1, h1b+asrc1+adst1 region (2.88M floats) is dead -> layer 2
    float* h2    = (float*)h1b;              // 40000*32
    float* asrc2 = h2 + 1280000;             // 40000
    float* adst2 = asrc2 + 40000;            // 40000
    float* agg2  = adst2 + 40000;            // 40000*32 (ends at 2.64M < 2.88M)

    hipMemsetAsync(cnt, 0, 40000 * sizeof(int), stream);

    // CSR build (shared by both layers)
    hist_kernel<<<(E_TOT + 255) / 256, 256, 0, stream>>>(eidx, cnt);
    scanA_kernel<<<SCAN_BLOCKS, 256, 0, stream>>>(cnt, rowptr, bsum);
    scanB_kernel<<<1, 256, 0, stream>>>(bsum, rowptr);
    scanC_kernel<<<SCAN_BLOCKS, 256, 0, stream>>>(rowptr, bsum, cnt);
    fill_kernel<<<(E_TOT + 255) / 256, 256, 0, stream>>>(eidx, rowptr, cnt, esrc);

    // Layer 1
    gemm1_kernel<<<625, 256, 0, stream>>>(x, W1, a_src1, a_dst1, h1b, asrc1, adst1);
    gather1_kernel<<<10000, 256, 0, stream>>>(rowptr, esrc, asrc1, adst1, h1b, b1, agg1);

    // Layer 2
    gemm2_kernel<<<625, 256, 0, stream>>>(agg1, W2, a_src2, a_dst2, h2, asrc2, adst2);
    gather2_kernel<<<5000, 256, 0, stream>>>(rowptr, esrc, asrc2, adst2, h2, b2, agg2);

    // Output projection
    out_gemm_kernel<<<1250, 256, 0, stream>>>(agg2, W_out, b_out, out);
}

// Round 5
// 183.865 us; speedup vs baseline: 4.2116x; 1.0005x over previous
//
#include <hip/hip_runtime.h>

#define N_NODES 40000
#define E_EDGES 640000
#define E_TOT   (E_EDGES + N_NODES)
#define SCAN_BLOCKS ((N_NODES + 255) / 256)   // 157

typedef unsigned int uint;
typedef unsigned short ushort;

// bf16 helpers (RNE pack, cheap unpack)
__device__ __forceinline__ ushort f2bf(float f) {
    uint u = __float_as_uint(f);
    u += 0x7FFFu + ((u >> 16) & 1u);
    return (ushort)(u >> 16);
}
__device__ __forceinline__ uint pk_bf(float lo, float hi) {
    return (uint)f2bf(lo) | ((uint)f2bf(hi) << 16);
}
__device__ __forceinline__ float bf_lo(uint w) { return __uint_as_float(w << 16); }
__device__ __forceinline__ float bf_hi(uint w) { return __uint_as_float(w & 0xFFFF0000u); }

// ===========================================================================
// Zero the histogram counters (replaces hipMemsetAsync: runtime fillBuffer
// kernel measured 42 us for 160 KB -- tiny-grid pathology).
// ===========================================================================
__global__ __launch_bounds__(256) void zero_cnt_kernel(int4* __restrict__ cnt4)
{
    const int i = blockIdx.x * 256 + threadIdx.x;
    if (i < 40064 / 4) cnt4[i] = make_int4(0, 0, 0, 0);
}

// ===========================================================================
// CSR build: histogram -> 3-kernel hierarchical scan -> fill.
// ===========================================================================
__global__ __launch_bounds__(256) void hist_kernel(
    const int* __restrict__ eidx, int* __restrict__ cnt)
{
    const int e = blockIdx.x * 256 + threadIdx.x;
    if (e >= E_TOT) return;
    const int d = (e < E_EDGES) ? eidx[E_EDGES + e] : e - E_EDGES;
    atomicAdd(&cnt[d], 1);
}

// Block-local exclusive scan of 256 contiguous elements; block total -> bsum.
__global__ __launch_bounds__(256) void scanA_kernel(
    const int* __restrict__ cnt, int* __restrict__ rowptr, int* __restrict__ bsum)
{
    const int i = blockIdx.x * 256 + threadIdx.x;
    const int lane = threadIdx.x & 63;
    const int wave = threadIdx.x >> 6;
    const int v = (i < N_NODES) ? cnt[i] : 0;
    int incl = v;
#pragma unroll
    for (int off = 1; off < 64; off <<= 1) {
        int u = __shfl_up(incl, off);
        if (lane >= off) incl += u;
    }
    __shared__ int ws[4];
    if (lane == 63) ws[wave] = incl;
    __syncthreads();
    int woff = 0;
    if (wave > 0) woff += ws[0];
    if (wave > 1) woff += ws[1];
    if (wave > 2) woff += ws[2];
    if (i < N_NODES) rowptr[i] = woff + incl - v;   // block-local exclusive
    if (threadIdx.x == 255) bsum[blockIdx.x] = woff + incl;
}

// Single block: exclusive scan of the block sums; write grand total.
__global__ __launch_bounds__(256) void scanB_kernel(
    int* __restrict__ bsum, int* __restrict__ rowptr)
{
    const int t = threadIdx.x;
    const int lane = t & 63;
    const int wave = t >> 6;
    const int v = (t < SCAN_BLOCKS) ? bsum[t] : 0;
    int incl = v;
#pragma unroll
    for (int off = 1; off < 64; off <<= 1) {
        int u = __shfl_up(incl, off);
        if (lane >= off) incl += u;
    }
    __shared__ int ws[4];
    if (lane == 63) ws[wave] = incl;
    __syncthreads();
    int woff = 0;
    if (wave > 0) woff += ws[0];
    if (wave > 1) woff += ws[1];
    if (wave > 2) woff += ws[2];
    if (t < SCAN_BLOCKS) bsum[t] = woff + incl - v;  // exclusive
    if (t == 255) rowptr[N_NODES] = woff + incl;     // grand total (v=0 here)
}

// Add block offsets; zero cnt for reuse as the fill cursor.
__global__ __launch_bounds__(256) void scanC_kernel(
    int* __restrict__ rowptr, const int* __restrict__ bsum, int* __restrict__ cnt)
{
    const int i = blockIdx.x * 256 + threadIdx.x;
    if (i >= N_NODES) return;
    rowptr[i] += bsum[blockIdx.x];
    cnt[i] = 0;
}

__global__ __launch_bounds__(256) void fill_kernel(
    const int* __restrict__ eidx, const int* __restrict__ rowptr,
    int* __restrict__ cursor, int* __restrict__ esrc)
{
    const int e = blockIdx.x * 256 + threadIdx.x;
    if (e >= E_TOT) return;
    int s, d;
    if (e < E_EDGES) { s = eidx[e]; d = eidx[E_EDGES + e]; }
    else             { s = d = e - E_EDGES; }
    const int pos = atomicAdd(&cursor[d], 1);
    esrc[rowptr[d] + pos] = s;
}

// ===========================================================================
// GEMM1: h1 = x @ W1  [40000x128 @ 128x128]; h1 stored as bf16 for the gather;
// attention coeffs computed from f32 accumulators (full precision).
// ===========================================================================
__global__ __launch_bounds__(256) void gemm1_kernel(
    const float* __restrict__ x, const float* __restrict__ W,
    const float* __restrict__ a_src, const float* __restrict__ a_dst,
    ushort* __restrict__ h1b, float* __restrict__ asrc, float* __restrict__ adst)
{
    __shared__ float Ws[128 * 128];   // 64 KB
    {
        const float4* Wg = (const float4*)W;
        float4* Wl = (float4*)Ws;
        for (int i = threadIdx.x; i < 128 * 128 / 4; i += 256) Wl[i] = Wg[i];
    }
    __syncthreads();
    const int row0 = blockIdx.x * 64;
    const int tx = threadIdx.x & 15;   // 16 col-groups of 8 cols
    const int ty = threadIdx.x >> 4;   // 16 row-groups of 4 rows

    float acc[4][8];
#pragma unroll
    for (int r = 0; r < 4; ++r)
#pragma unroll
        for (int c = 0; c < 8; ++c) acc[r][c] = 0.f;

    for (int k0 = 0; k0 < 128; k0 += 4) {
        float xv[4][4];
#pragma unroll
        for (int r = 0; r < 4; ++r) {
            float4 t = *(const float4*)&x[(size_t)(row0 + ty * 4 + r) * 128 + k0];
            xv[r][0] = t.x; xv[r][1] = t.y; xv[r][2] = t.z; xv[r][3] = t.w;
        }
#pragma unroll
        for (int kk = 0; kk < 4; ++kk) {
            float wreg[8];
            float4 w0 = *(const float4*)&Ws[(k0 + kk) * 128 + tx * 8];
            float4 w1 = *(const float4*)&Ws[(k0 + kk) * 128 + tx * 8 + 4];
            wreg[0] = w0.x; wreg[1] = w0.y; wreg[2] = w0.z; wreg[3] = w0.w;
            wreg[4] = w1.x; wreg[5] = w1.y; wreg[6] = w1.z; wreg[7] = w1.w;
#pragma unroll
            for (int r = 0; r < 4; ++r)
#pragma unroll
                for (int c = 0; c < 8; ++c)
                    acc[r][c] = fmaf(xv[r][kk], wreg[c], acc[r][c]);
        }
    }

    const int head  = tx >> 2;
    const int cbase = (tx & 3) * 8;
    float as[8], ad[8];
#pragma unroll
    for (int c = 0; c < 8; ++c) {
        as[c] = a_src[head * 32 + cbase + c];
        ad[c] = a_dst[head * 32 + cbase + c];
    }
#pragma unroll
    for (int r = 0; r < 4; ++r) {
        const int n = row0 + ty * 4 + r;
        uint4 o;
        o.x = pk_bf(acc[r][0], acc[r][1]);
        o.y = pk_bf(acc[r][2], acc[r][3]);
        o.z = pk_bf(acc[r][4], acc[r][5]);
        o.w = pk_bf(acc[r][6], acc[r][7]);
        *(uint4*)&h1b[(size_t)n * 128 + tx * 8] = o;
        float ps = 0.f, pd = 0.f;
#pragma unroll
        for (int c = 0; c < 8; ++c) {
            ps = fmaf(acc[r][c], as[c], ps);
            pd = fmaf(acc[r][c], ad[c], pd);
        }
        ps += __shfl_xor(ps, 1); ps += __shfl_xor(ps, 2);
        pd += __shfl_xor(pd, 1); pd += __shfl_xor(pd, 2);
        if ((threadIdx.x & 3) == 0) {
            asrc[n * 4 + head] = ps;
            adst[n * 4 + head] = pd;
        }
    }
}

// ===========================================================================
// Gather pass 1: one wave per dst node, bf16 h1 rows (256 B), 4-deep manual
// memory pipeline; fused normalize + bias + ELU.
// ===========================================================================
__global__ __launch_bounds__(256) void gather1_kernel(
    const int* __restrict__ rowptr, const int* __restrict__ esrc,
    const float* __restrict__ asrc, const float* __restrict__ adst,
    const ushort* __restrict__ h1b, const float* __restrict__ b,
    float* __restrict__ agg)
{
    const int node = (blockIdx.x * 256 + threadIdx.x) >> 6;
    const int lane = threadIdx.x & 63;
    if (node >= N_NODES) return;
    const int head = lane >> 4;
    const float ad = adst[node * 4 + head];
    const int beg = rowptr[node], end = rowptr[node + 1];
    float acc0 = 0.f, acc1 = 0.f, den = 0.f;

    int i = beg;
    for (; i + 4 <= end; i += 4) {
        const int s0 = esrc[i], s1 = esrc[i + 1], s2 = esrc[i + 2], s3 = esrc[i + 3];
        const float a0 = asrc[s0 * 4 + head];
        const float a1 = asrc[s1 * 4 + head];
        const float a2 = asrc[s2 * 4 + head];
        const float a3 = asrc[s3 * 4 + head];
        const uint w0 = *(const uint*)&h1b[(size_t)s0 * 128 + lane * 2];
        const uint w1 = *(const uint*)&h1b[(size_t)s1 * 128 + lane * 2];
        const uint w2 = *(const uint*)&h1b[(size_t)s2 * 128 + lane * 2];
        const uint w3 = *(const uint*)&h1b[(size_t)s3 * 128 + lane * 2];
        float v0 = a0 + ad; v0 = v0 > 0.f ? v0 : 0.2f * v0;
        float v1 = a1 + ad; v1 = v1 > 0.f ? v1 : 0.2f * v1;
        float v2 = a2 + ad; v2 = v2 > 0.f ? v2 : 0.2f * v2;
        float v3 = a3 + ad; v3 = v3 > 0.f ? v3 : 0.2f * v3;
        const float e0 = __expf(v0), e1 = __expf(v1), e2 = __expf(v2), e3 = __expf(v3);
        den += (e0 + e1) + (e2 + e3);
        acc0 = fmaf(e0, bf_lo(w0), acc0); acc1 = fmaf(e0, bf_hi(w0), acc1);
        acc0 = fmaf(e1, bf_lo(w1), acc0); acc1 = fmaf(e1, bf_hi(w1), acc1);
        acc0 = fmaf(e2, bf_lo(w2), acc0); acc1 = fmaf(e2, bf_hi(w2), acc1);
        acc0 = fmaf(e3, bf_lo(w3), acc0); acc1 = fmaf(e3, bf_hi(w3), acc1);
    }
    for (; i < end; ++i) {
        const int s = esrc[i];
        float av = asrc[s * 4 + head] + ad;
        av = av > 0.f ? av : 0.2f * av;
        const float ex = __expf(av);
        const uint w = *(const uint*)&h1b[(size_t)s * 128 + lane * 2];
        den += ex;
        acc0 = fmaf(ex, bf_lo(w), acc0);
        acc1 = fmaf(ex, bf_hi(w), acc1);
    }

    const float inv = 1.f / (den + 1e-16f);
    const float2 bv = *(const float2*)&b[lane * 2];
    float o0 = acc0 * inv + bv.x;
    float o1 = acc1 * inv + bv.y;
    o0 = o0 > 0.f ? o0 : expm1f(o0);
    o1 = o1 > 0.f ? o1 : expm1f(o1);
    *(float2*)&agg[(size_t)node * 128 + lane * 2] = make_float2(o0, o1);
}

// ===========================================================================
// GEMM2: h2 = hin @ W2  [40000x128 @ 128x32], fused attention coeffs (1 head)
// ===========================================================================
__global__ __launch_bounds__(256) void gemm2_kernel(
    const float* __restrict__ hin, const float* __restrict__ W,
    const float* __restrict__ a_src, const float* __restrict__ a_dst,
    float* __restrict__ h2, float* __restrict__ asrc, float* __restrict__ adst)
{
    __shared__ float Ws[128 * 32];   // 16 KB
    {
        const float4* Wg = (const float4*)W;
        float4* Wl = (float4*)Ws;
        for (int i = threadIdx.x; i < 128 * 32 / 4; i += 256) Wl[i] = Wg[i];
    }
    __syncthreads();
    const int row0 = blockIdx.x * 64;
    const int tx = threadIdx.x & 7;
    const int ty = threadIdx.x >> 3;

    float acc[2][4];
#pragma unroll
    for (int r = 0; r < 2; ++r)
#pragma unroll
        for (int c = 0; c < 4; ++c) acc[r][c] = 0.f;

    for (int k0 = 0; k0 < 128; k0 += 4) {
        float xv[2][4];
#pragma unroll
        for (int r = 0; r < 2; ++r) {
            float4 t = *(const float4*)&hin[(size_t)(row0 + ty * 2 + r) * 128 + k0];
            xv[r][0] = t.x; xv[r][1] = t.y; xv[r][2] = t.z; xv[r][3] = t.w;
        }
#pragma unroll
        for (int kk = 0; kk < 4; ++kk) {
            float4 w = *(const float4*)&Ws[(k0 + kk) * 32 + tx * 4];
            float wreg[4] = { w.x, w.y, w.z, w.w };
#pragma unroll
            for (int r = 0; r < 2; ++r)
#pragma unroll
                for (int c = 0; c < 4; ++c)
                    acc[r][c] = fmaf(xv[r][kk], wreg[c], acc[r][c]);
        }
    }

    float as[4], ad[4];
#pragma unroll
    for (int c = 0; c < 4; ++c) {
        as[c] = a_src[tx * 4 + c];
        ad[c] = a_dst[tx * 4 + c];
    }
#pragma unroll
    for (int r = 0; r < 2; ++r) {
        const int n = row0 + ty * 2 + r;
        *(float4*)&h2[(size_t)n * 32 + tx * 4] =
            make_float4(acc[r][0], acc[r][1], acc[r][2], acc[r][3]);
        float ps = 0.f, pd = 0.f;
#pragma unroll
        for (int c = 0; c < 4; ++c) {
            ps = fmaf(acc[r][c], as[c], ps);
            pd = fmaf(acc[r][c], ad[c], pd);
        }
        ps += __shfl_xor(ps, 1); ps += __shfl_xor(ps, 2); ps += __shfl_xor(ps, 4);
        pd += __shfl_xor(pd, 1); pd += __shfl_xor(pd, 2); pd += __shfl_xor(pd, 4);
        if ((threadIdx.x & 7) == 0) { asrc[n] = ps; adst[n] = pd; }
    }
}

// ===========================================================================
// Gather pass 2: 32 lanes per dst node, 4-deep pipeline; fused norm+bias+ELU.
// ===========================================================================
__global__ __launch_bounds__(256) void gather2_kernel(
    const int* __restrict__ rowptr, const int* __restrict__ esrc,
    const float* __restrict__ asrc, const float* __restrict__ adst,
    const float* __restrict__ h2, const float* __restrict__ b,
    float* __restrict__ agg)
{
    const int t = blockIdx.x * 256 + threadIdx.x;
    const int node = t >> 5;
    const int c = t & 31;
    if (node >= N_NODES) return;
    const float ad = adst[node];
    const int beg = rowptr[node], end = rowptr[node + 1];
    float acc = 0.f, den = 0.f;

    int i = beg;
    for (; i + 4 <= end; i += 4) {
        const int s0 = esrc[i], s1 = esrc[i + 1], s2 = esrc[i + 2], s3 = esrc[i + 3];
        const float a0 = asrc[s0], a1 = asrc[s1], a2 = asrc[s2], a3 = asrc[s3];
        const float h0 = h2[(size_t)s0 * 32 + c];
        const float h1 = h2[(size_t)s1 * 32 + c];
        const float hh2 = h2[(size_t)s2 * 32 + c];
        const float h3 = h2[(size_t)s3 * 32 + c];
        float v0 = a0 + ad; v0 = v0 > 0.f ? v0 : 0.2f * v0;
        float v1 = a1 + ad; v1 = v1 > 0.f ? v1 : 0.2f * v1;
        float v2 = a2 + ad; v2 = v2 > 0.f ? v2 : 0.2f * v2;
        float v3 = a3 + ad; v3 = v3 > 0.f ? v3 : 0.2f * v3;
        const float e0 = __expf(v0), e1 = __expf(v1), e2 = __expf(v2), e3 = __expf(v3);
        den += (e0 + e1) + (e2 + e3);
        acc = fmaf(e0, h0, acc);
        acc = fmaf(e1, h1, acc);
        acc = fmaf(e2, hh2, acc);
        acc = fmaf(e3, h3, acc);
    }
    for (; i < end; ++i) {
        const int s = esrc[i];
        float av = asrc[s] + ad;
        av = av > 0.f ? av : 0.2f * av;
        const float ex = __expf(av);
        den += ex;
        acc = fmaf(ex, h2[(size_t)s * 32 + c], acc);
    }

    const float inv = 1.f / (den + 1e-16f);
    float o = acc * inv + b[c];
    o = o > 0.f ? o : expm1f(o);
    agg[(size_t)node * 32 + c] = o;
}

// ===========================================================================
// Output GEMM: out = h3 @ W_out + b_out  [40000x32 @ 32x112]
// ===========================================================================
__global__ __launch_bounds__(256) void out_gemm_kernel(
    const float* __restrict__ h3, const float* __restrict__ W,
    const float* __restrict__ b, float* __restrict__ out)
{
    __shared__ float Ws[32 * 112];   // 14 KB
    {
        const float4* Wg = (const float4*)W;
        float4* Wl = (float4*)Ws;
        for (int i = threadIdx.x; i < 32 * 112 / 4; i += 256) Wl[i] = Wg[i];
    }
    __syncthreads();
    const int row0 = blockIdx.x * 32;
    const int tc = threadIdx.x & 15;
    const int tr = threadIdx.x >> 4;

    float acc[2][7];
#pragma unroll
    for (int r = 0; r < 2; ++r)
#pragma unroll
        for (int c = 0; c < 7; ++c) acc[r][c] = 0.f;

    for (int k0 = 0; k0 < 32; k0 += 4) {
        float xv[2][4];
#pragma unroll
        for (int r = 0; r < 2; ++r) {
            float4 t = *(const float4*)&h3[(size_t)(row0 + tr * 2 + r) * 32 + k0];
            xv[r][0] = t.x; xv[r][1] = t.y; xv[r][2] = t.z; xv[r][3] = t.w;
        }
#pragma unroll
        for (int kk = 0; kk < 4; ++kk) {
            float wv[7];
#pragma unroll
            for (int c = 0; c < 7; ++c) wv[c] = Ws[(k0 + kk) * 112 + tc * 7 + c];
#pragma unroll
            for (int r = 0; r < 2; ++r)
#pragma unroll
                for (int c = 0; c < 7; ++c)
                    acc[r][c] = fmaf(xv[r][kk], wv[c], acc[r][c]);
        }
    }
#pragma unroll
    for (int r = 0; r < 2; ++r) {
        const int n = row0 + tr * 2 + r;
#pragma unroll
        for (int c = 0; c < 7; ++c)
            out[(size_t)n * 112 + tc * 7 + c] = acc[r][c] + b[tc * 7 + c];
    }
}

// ===========================================================================
extern "C" void kernel_launch(void* const* d_in, const int* in_sizes, int n_in,
                              void* d_out, int out_size, void* d_ws, size_t ws_size,
                              hipStream_t stream) {
    const float* x      = (const float*)d_in[0];
    const int*   eidx   = (const int*)d_in[1];
    const float* W1     = (const float*)d_in[2];
    const float* a_src1 = (const float*)d_in[3];
    const float* a_dst1 = (const float*)d_in[4];
    const float* b1     = (const float*)d_in[5];
    const float* W2     = (const float*)d_in[6];
    const float* a_src2 = (const float*)d_in[7];
    const float* a_dst2 = (const float*)d_in[8];
    const float* b2     = (const float*)d_in[9];
    const float* W_out  = (const float*)d_in[10];
    const float* b_out  = (const float*)d_in[11];
    float* out = (float*)d_out;

    // ---- workspace layout (~35 MB) ----
    int* rowptr = (int*)d_ws;                // 40064
    int* cnt    = rowptr + 40064;            // 40064 (hist counts, then fill cursor)
    int* bsum   = cnt + 40064;               // 192 (block sums for the scan)
    int* esrc   = bsum + 192;                // 680000 CSR edge sources
    ushort* h1b  = (ushort*)(esrc + 680000); // 40000*128 bf16
    float* asrc1 = (float*)(h1b + 5120000);  // 40000*4
    float* adst1 = asrc1 + 160000;           // 40000*4
    float* agg1  = adst1 + 160000;           // 40000*128
    // after gather1, h1b+asrc1+adst1 region (2.88M floats) is dead -> layer 2
    float* h2    = (float*)h1b;              // 40000*32
    float* asrc2 = h2 + 1280000;             // 40000
    float* adst2 = asrc2 + 40000;            // 40000
    float* agg2  = adst2 + 40000;            // 40000*32 (ends at 2.64M < 2.88M)

    // CSR build (shared by both layers)
    zero_cnt_kernel<<<(40064 / 4 + 255) / 256, 256, 0, stream>>>((int4*)cnt);
    hist_kernel<<<(E_TOT + 255) / 256, 256, 0, stream>>>(eidx, cnt);
    scanA_kernel<<<SCAN_BLOCKS, 256, 0, stream>>>(cnt, rowptr, bsum);
    scanB_kernel<<<1, 256, 0, stream>>>(bsum, rowptr);
    scanC_kernel<<<SCAN_BLOCKS, 256, 0, stream>>>(rowptr, bsum, cnt);
    fill_kernel<<<(E_TOT + 255) / 256, 256, 0, stream>>>(eidx, rowptr, cnt, esrc);

    // Layer 1
    gemm1_kernel<<<625, 256, 0, stream>>>(x, W1, a_src1, a_dst1, h1b, asrc1, adst1);
    gather1_kernel<<<10000, 256, 0, stream>>>(rowptr, esrc, asrc1, adst1, h1b, b1, agg1);

    // Layer 2
    gemm2_kernel<<<625, 256, 0, stream>>>(agg1, W2, a_src2, a_dst2, h2, asrc2, adst2);
    gather2_kernel<<<5000, 256, 0, stream>>>(rowptr, esrc, asrc2, adst2, h2, b2, agg2);

    // Output projection
    out_gemm_kernel<<<1250, 256, 0, stream>>>(agg2, W_out, b_out, out);
}

// Round 6
// 177.194 us; speedup vs baseline: 4.3701x; 1.0376x over previous
//
#include <hip/hip_runtime.h>

#define N_NODES 40000
#define E_EDGES 640000
#define E_TOT   (E_EDGES + N_NODES)
#define SCAN_BLOCKS ((N_NODES + 255) / 256)   // 157

typedef unsigned int uint;
typedef unsigned short ushort;

// bf16 helpers (RNE pack, cheap unpack)
__device__ __forceinline__ ushort f2bf(float f) {
    uint u = __float_as_uint(f);
    u += 0x7FFFu + ((u >> 16) & 1u);
    return (ushort)(u >> 16);
}
__device__ __forceinline__ uint pk_bf(float lo, float hi) {
    return (uint)f2bf(lo) | ((uint)f2bf(hi) << 16);
}
__device__ __forceinline__ float bf_lo(uint w) { return __uint_as_float(w << 16); }
__device__ __forceinline__ float bf_hi(uint w) { return __uint_as_float(w & 0xFFFF0000u); }

// ===========================================================================
// CSR build: histogram -> 2-kernel scan (block offsets folded into consumers)
// -> fill (also precomputes per-edge softmax numerators for layer 1).
// ===========================================================================
__global__ __launch_bounds__(256) void hist_kernel(
    const int* __restrict__ eidx, int* __restrict__ cnt)
{
    const int e = blockIdx.x * 256 + threadIdx.x;
    if (e >= E_TOT) return;
    const int d = (e < E_EDGES) ? eidx[E_EDGES + e] : e - E_EDGES;
    atomicAdd(&cnt[d], 1);
}

// Block-local exclusive scan of 256 contiguous elements (incl. i == N_NODES
// boundary slot); block total -> bsum; zeroes the fill cursor.
__global__ __launch_bounds__(256) void scanA_kernel(
    const int* __restrict__ cnt, int* __restrict__ rowptr, int* __restrict__ bsum,
    int* __restrict__ cursor)
{
    const int i = blockIdx.x * 256 + threadIdx.x;
    const int lane = threadIdx.x & 63;
    const int wave = threadIdx.x >> 6;
    const int v = (i < N_NODES) ? cnt[i] : 0;
    int incl = v;
#pragma unroll
    for (int off = 1; off < 64; off <<= 1) {
        int u = __shfl_up(incl, off);
        if (lane >= off) incl += u;
    }
    __shared__ int ws[4];
    if (lane == 63) ws[wave] = incl;
    __syncthreads();
    int woff = 0;
    if (wave > 0) woff += ws[0];
    if (wave > 1) woff += ws[1];
    if (wave > 2) woff += ws[2];
    if (i <= N_NODES) rowptr[i] = woff + incl - v;   // block-local exclusive
    if (i < N_NODES) cursor[i] = 0;
    if (threadIdx.x == 255) bsum[blockIdx.x] = woff + incl;
}

// Single block: exclusive scan of the 157 block sums in place.
__global__ __launch_bounds__(256) void scanB_kernel(int* __restrict__ bsum)
{
    const int t = threadIdx.x;
    const int lane = t & 63;
    const int wave = t >> 6;
    const int v = (t < SCAN_BLOCKS) ? bsum[t] : 0;
    int incl = v;
#pragma unroll
    for (int off = 1; off < 64; off <<= 1) {
        int u = __shfl_up(incl, off);
        if (lane >= off) incl += u;
    }
    __shared__ int ws[4];
    if (lane == 63) ws[wave] = incl;
    __syncthreads();
    int woff = 0;
    if (wave > 0) woff += ws[0];
    if (wave > 1) woff += ws[1];
    if (wave > 2) woff += ws[2];
    if (t < SCAN_BLOCKS) bsum[t] = woff + incl - v;  // exclusive
}

// Bucket edges by dst; also precompute layer-1 per-edge softmax numerators
// ex1[p*4+h] = exp(leaky_relu(asrc1[s,h] + adst1[d,h])) (gemm1 ran already).
__global__ __launch_bounds__(256) void fill_kernel(
    const int* __restrict__ eidx, const int* __restrict__ rowptr,
    const int* __restrict__ bsum, int* __restrict__ cursor,
    const float* __restrict__ asrc, const float* __restrict__ adst,
    int* __restrict__ esrc, float* __restrict__ ex1)
{
    const int e = blockIdx.x * 256 + threadIdx.x;
    if (e >= E_TOT) return;
    int s, d;
    if (e < E_EDGES) { s = eidx[e]; d = eidx[E_EDGES + e]; }
    else             { s = d = e - E_EDGES; }
    const int pos = atomicAdd(&cursor[d], 1);
    const int p = rowptr[d] + bsum[d >> 8] + pos;
    esrc[p] = s;
    const float4 as = *(const float4*)&asrc[s * 4];
    const float4 ad = *(const float4*)&adst[d * 4];
    float v0 = as.x + ad.x; v0 = v0 > 0.f ? v0 : 0.2f * v0;
    float v1 = as.y + ad.y; v1 = v1 > 0.f ? v1 : 0.2f * v1;
    float v2 = as.z + ad.z; v2 = v2 > 0.f ? v2 : 0.2f * v2;
    float v3 = as.w + ad.w; v3 = v3 > 0.f ? v3 : 0.2f * v3;
    *(float4*)&ex1[(size_t)p * 4] =
        make_float4(__expf(v0), __expf(v1), __expf(v2), __expf(v3));
}

// ===========================================================================
// GEMM1: h1 = x @ W1  [40000x128 @ 128x128]; h1 stored as bf16 for the gather;
// attention coeffs from f32 accumulators. Also zeroes cnt (runs first).
// ===========================================================================
__global__ __launch_bounds__(256) void gemm1_kernel(
    const float* __restrict__ x, const float* __restrict__ W,
    const float* __restrict__ a_src, const float* __restrict__ a_dst,
    ushort* __restrict__ h1b, float* __restrict__ asrc, float* __restrict__ adst,
    int4* __restrict__ cnt4)
{
    if (blockIdx.x < 40) {
        const int idx = blockIdx.x * 256 + threadIdx.x;
        if (idx < 40064 / 4) cnt4[idx] = make_int4(0, 0, 0, 0);
    }
    __shared__ float Ws[128 * 128];   // 64 KB
    {
        const float4* Wg = (const float4*)W;
        float4* Wl = (float4*)Ws;
        for (int i = threadIdx.x; i < 128 * 128 / 4; i += 256) Wl[i] = Wg[i];
    }
    __syncthreads();
    const int row0 = blockIdx.x * 64;
    const int tx = threadIdx.x & 15;   // 16 col-groups of 8 cols
    const int ty = threadIdx.x >> 4;   // 16 row-groups of 4 rows

    float acc[4][8];
#pragma unroll
    for (int r = 0; r < 4; ++r)
#pragma unroll
        for (int c = 0; c < 8; ++c) acc[r][c] = 0.f;

    for (int k0 = 0; k0 < 128; k0 += 4) {
        float xv[4][4];
#pragma unroll
        for (int r = 0; r < 4; ++r) {
            float4 t = *(const float4*)&x[(size_t)(row0 + ty * 4 + r) * 128 + k0];
            xv[r][0] = t.x; xv[r][1] = t.y; xv[r][2] = t.z; xv[r][3] = t.w;
        }
#pragma unroll
        for (int kk = 0; kk < 4; ++kk) {
            float wreg[8];
            float4 w0 = *(const float4*)&Ws[(k0 + kk) * 128 + tx * 8];
            float4 w1 = *(const float4*)&Ws[(k0 + kk) * 128 + tx * 8 + 4];
            wreg[0] = w0.x; wreg[1] = w0.y; wreg[2] = w0.z; wreg[3] = w0.w;
            wreg[4] = w1.x; wreg[5] = w1.y; wreg[6] = w1.z; wreg[7] = w1.w;
#pragma unroll
            for (int r = 0; r < 4; ++r)
#pragma unroll
                for (int c = 0; c < 8; ++c)
                    acc[r][c] = fmaf(xv[r][kk], wreg[c], acc[r][c]);
        }
    }

    const int head  = tx >> 2;
    const int cbase = (tx & 3) * 8;
    float as[8], ad[8];
#pragma unroll
    for (int c = 0; c < 8; ++c) {
        as[c] = a_src[head * 32 + cbase + c];
        ad[c] = a_dst[head * 32 + cbase + c];
    }
#pragma unroll
    for (int r = 0; r < 4; ++r) {
        const int n = row0 + ty * 4 + r;
        uint4 o;
        o.x = pk_bf(acc[r][0], acc[r][1]);
        o.y = pk_bf(acc[r][2], acc[r][3]);
        o.z = pk_bf(acc[r][4], acc[r][5]);
        o.w = pk_bf(acc[r][6], acc[r][7]);
        *(uint4*)&h1b[(size_t)n * 128 + tx * 8] = o;
        float ps = 0.f, pd = 0.f;
#pragma unroll
        for (int c = 0; c < 8; ++c) {
            ps = fmaf(acc[r][c], as[c], ps);
            pd = fmaf(acc[r][c], ad[c], pd);
        }
        ps += __shfl_xor(ps, 1); ps += __shfl_xor(ps, 2);
        pd += __shfl_xor(pd, 1); pd += __shfl_xor(pd, 2);
        if ((threadIdx.x & 3) == 0) {
            asrc[n * 4 + head] = ps;
            adst[n * 4 + head] = pd;
        }
    }
}

// ===========================================================================
// Gather pass 1: one wave per dst node. Streaming esrc/ex1 + random bf16 row,
// 8-deep memory pipeline; fused normalize + bias + ELU.
// ===========================================================================
__global__ __launch_bounds__(256) void gather1_kernel(
    const int* __restrict__ rowptr, const int* __restrict__ bsum,
    const int* __restrict__ esrc, const float* __restrict__ ex1,
    const ushort* __restrict__ h1b, const float* __restrict__ b,
    float* __restrict__ agg)
{
    const int node = (blockIdx.x * 256 + threadIdx.x) >> 6;
    const int lane = threadIdx.x & 63;
    if (node >= N_NODES) return;
    const int head = lane >> 4;
    const int beg = rowptr[node] + bsum[node >> 8];
    const int end = rowptr[node + 1] + bsum[(node + 1) >> 8];
    float acc0 = 0.f, acc1 = 0.f, den = 0.f;

    int i = beg;
    for (; i + 8 <= end; i += 8) {
        int s[8];
        float e[8];
        uint w[8];
#pragma unroll
        for (int j = 0; j < 8; ++j) s[j] = esrc[i + j];
#pragma unroll
        for (int j = 0; j < 8; ++j) e[j] = ex1[(size_t)(i + j) * 4 + head];
#pragma unroll
        for (int j = 0; j < 8; ++j)
            w[j] = *(const uint*)&h1b[(size_t)s[j] * 128 + lane * 2];
#pragma unroll
        for (int j = 0; j < 8; ++j) {
            den += e[j];
            acc0 = fmaf(e[j], bf_lo(w[j]), acc0);
            acc1 = fmaf(e[j], bf_hi(w[j]), acc1);
        }
    }
    for (; i < end; ++i) {
        const int s = esrc[i];
        const float e = ex1[(size_t)i * 4 + head];
        const uint w = *(const uint*)&h1b[(size_t)s * 128 + lane * 2];
        den += e;
        acc0 = fmaf(e, bf_lo(w), acc0);
        acc1 = fmaf(e, bf_hi(w), acc1);
    }

    const float inv = 1.f / (den + 1e-16f);
    const float2 bv = *(const float2*)&b[lane * 2];
    float o0 = acc0 * inv + bv.x;
    float o1 = acc1 * inv + bv.y;
    o0 = o0 > 0.f ? o0 : expm1f(o0);
    o1 = o1 > 0.f ? o1 : expm1f(o1);
    *(float2*)&agg[(size_t)node * 128 + lane * 2] = make_float2(o0, o1);
}

// ===========================================================================
// GEMM2: h2 = hin @ W2  [40000x128 @ 128x32], fused attention coeffs (1 head)
// ===========================================================================
__global__ __launch_bounds__(256) void gemm2_kernel(
    const float* __restrict__ hin, const float* __restrict__ W,
    const float* __restrict__ a_src, const float* __restrict__ a_dst,
    float* __restrict__ h2, float* __restrict__ asrc, float* __restrict__ adst)
{
    __shared__ float Ws[128 * 32];   // 16 KB
    {
        const float4* Wg = (const float4*)W;
        float4* Wl = (float4*)Ws;
        for (int i = threadIdx.x; i < 128 * 32 / 4; i += 256) Wl[i] = Wg[i];
    }
    __syncthreads();
    const int row0 = blockIdx.x * 64;
    const int tx = threadIdx.x & 7;
    const int ty = threadIdx.x >> 3;

    float acc[2][4];
#pragma unroll
    for (int r = 0; r < 2; ++r)
#pragma unroll
        for (int c = 0; c < 4; ++c) acc[r][c] = 0.f;

    for (int k0 = 0; k0 < 128; k0 += 4) {
        float xv[2][4];
#pragma unroll
        for (int r = 0; r < 2; ++r) {
            float4 t = *(const float4*)&hin[(size_t)(row0 + ty * 2 + r) * 128 + k0];
            xv[r][0] = t.x; xv[r][1] = t.y; xv[r][2] = t.z; xv[r][3] = t.w;
        }
#pragma unroll
        for (int kk = 0; kk < 4; ++kk) {
            float4 w = *(const float4*)&Ws[(k0 + kk) * 32 + tx * 4];
            float wreg[4] = { w.x, w.y, w.z, w.w };
#pragma unroll
            for (int r = 0; r < 2; ++r)
#pragma unroll
                for (int c = 0; c < 4; ++c)
                    acc[r][c] = fmaf(xv[r][kk], wreg[c], acc[r][c]);
        }
    }

    float as[4], ad[4];
#pragma unroll
    for (int c = 0; c < 4; ++c) {
        as[c] = a_src[tx * 4 + c];
        ad[c] = a_dst[tx * 4 + c];
    }
#pragma unroll
    for (int r = 0; r < 2; ++r) {
        const int n = row0 + ty * 2 + r;
        *(float4*)&h2[(size_t)n * 32 + tx * 4] =
            make_float4(acc[r][0], acc[r][1], acc[r][2], acc[r][3]);
        float ps = 0.f, pd = 0.f;
#pragma unroll
        for (int c = 0; c < 4; ++c) {
            ps = fmaf(acc[r][c], as[c], ps);
            pd = fmaf(acc[r][c], ad[c], pd);
        }
        ps += __shfl_xor(ps, 1); ps += __shfl_xor(ps, 2); ps += __shfl_xor(ps, 4);
        pd += __shfl_xor(pd, 1); pd += __shfl_xor(pd, 2); pd += __shfl_xor(pd, 4);
        if ((threadIdx.x & 7) == 0) { asrc[n] = ps; adst[n] = pd; }
    }
}

// ===========================================================================
// Gather pass 2: 32 lanes per dst node, 8-deep pipeline; fused norm+bias+ELU.
// ===========================================================================
__global__ __launch_bounds__(256) void gather2_kernel(
    const int* __restrict__ rowptr, const int* __restrict__ bsum,
    const int* __restrict__ esrc,
    const float* __restrict__ asrc, const float* __restrict__ adst,
    const float* __restrict__ h2, const float* __restrict__ b,
    float* __restrict__ agg)
{
    const int t = blockIdx.x * 256 + threadIdx.x;
    const int node = t >> 5;
    const int c = t & 31;
    if (node >= N_NODES) return;
    const float ad = adst[node];
    const int beg = rowptr[node] + bsum[node >> 8];
    const int end = rowptr[node + 1] + bsum[(node + 1) >> 8];
    float acc = 0.f, den = 0.f;

    int i = beg;
    for (; i + 8 <= end; i += 8) {
        int s[8];
        float a[8], h[8];
#pragma unroll
        for (int j = 0; j < 8; ++j) s[j] = esrc[i + j];
#pragma unroll
        for (int j = 0; j < 8; ++j) a[j] = asrc[s[j]];
#pragma unroll
        for (int j = 0; j < 8; ++j) h[j] = h2[(size_t)s[j] * 32 + c];
#pragma unroll
        for (int j = 0; j < 8; ++j) {
            float v = a[j] + ad; v = v > 0.f ? v : 0.2f * v;
            const float e = __expf(v);
            den += e;
            acc = fmaf(e, h[j], acc);
        }
    }
    for (; i < end; ++i) {
        const int s = esrc[i];
        float av = asrc[s] + ad;
        av = av > 0.f ? av : 0.2f * av;
        const float ex = __expf(av);
        den += ex;
        acc = fmaf(ex, h2[(size_t)s * 32 + c], acc);
    }

    const float inv = 1.f / (den + 1e-16f);
    float o = acc * inv + b[c];
    o = o > 0.f ? o : expm1f(o);
    agg[(size_t)node * 32 + c] = o;
}

// ===========================================================================
// Output GEMM: out = h3 @ W_out + b_out  [40000x32 @ 32x112]
// ===========================================================================
__global__ __launch_bounds__(256) void out_gemm_kernel(
    const float* __restrict__ h3, const float* __restrict__ W,
    const float* __restrict__ b, float* __restrict__ out)
{
    __shared__ float Ws[32 * 112];   // 14 KB
    {
        const float4* Wg = (const float4*)W;
        float4* Wl = (float4*)Ws;
        for (int i = threadIdx.x; i < 32 * 112 / 4; i += 256) Wl[i] = Wg[i];
    }
    __syncthreads();
    const int row0 = blockIdx.x * 32;
    const int tc = threadIdx.x & 15;
    const int tr = threadIdx.x >> 4;

    float acc[2][7];
#pragma unroll
    for (int r = 0; r < 2; ++r)
#pragma unroll
        for (int c = 0; c < 7; ++c) acc[r][c] = 0.f;

    for (int k0 = 0; k0 < 32; k0 += 4) {
        float xv[2][4];
#pragma unroll
        for (int r = 0; r < 2; ++r) {
            float4 t = *(const float4*)&h3[(size_t)(row0 + tr * 2 + r) * 32 + k0];
            xv[r][0] = t.x; xv[r][1] = t.y; xv[r][2] = t.z; xv[r][3] = t.w;
        }
#pragma unroll
        for (int kk = 0; kk < 4; ++kk) {
            float wv[7];
#pragma unroll
            for (int c = 0; c < 7; ++c) wv[c] = Ws[(k0 + kk) * 112 + tc * 7 + c];
#pragma unroll
            for (int r = 0; r < 2; ++r)
#pragma unroll
                for (int c = 0; c < 7; ++c)
                    acc[r][c] = fmaf(xv[r][kk], wv[c], acc[r][c]);
        }
    }
#pragma unroll
    for (int r = 0; r < 2; ++r) {
        const int n = row0 + tr * 2 + r;
#pragma unroll
        for (int c = 0; c < 7; ++c)
            out[(size_t)n * 112 + tc * 7 + c] = acc[r][c] + b[tc * 7 + c];
    }
}

// ===========================================================================
extern "C" void kernel_launch(void* const* d_in, const int* in_sizes, int n_in,
                              void* d_out, int out_size, void* d_ws, size_t ws_size,
                              hipStream_t stream) {
    const float* x      = (const float*)d_in[0];
    const int*   eidx   = (const int*)d_in[1];
    const float* W1     = (const float*)d_in[2];
    const float* a_src1 = (const float*)d_in[3];
    const float* a_dst1 = (const float*)d_in[4];
    const float* b1     = (const float*)d_in[5];
    const float* W2     = (const float*)d_in[6];
    const float* a_src2 = (const float*)d_in[7];
    const float* a_dst2 = (const float*)d_in[8];
    const float* b2     = (const float*)d_in[9];
    const float* W_out  = (const float*)d_in[10];
    const float* b_out  = (const float*)d_in[11];
    float* out = (float*)d_out;

    // ---- workspace layout (~46 MB), all segment sizes multiples of 16 words
    int* rowptr = (int*)d_ws;                // 40064 (uses [0..40000])
    int* cnt    = rowptr + 40064;            // 40064 histogram counts
    int* cursor = cnt + 40064;               // 40064 fill cursor
    int* bsum   = cursor + 40064;            // 192 block sums (exclusive)
    int* esrc   = bsum + 192;                // 680000 CSR edge sources
    float* ex1   = (float*)(esrc + 680000);  // 680000*4 layer-1 edge numerators
    ushort* h1b  = (ushort*)(ex1 + 2720000); // 40000*128 bf16
    float* asrc1 = (float*)(h1b + 5120000);  // 40000*4
    float* adst1 = asrc1 + 160000;           // 40000*4
    float* agg1  = adst1 + 160000;           // 40000*128
    // after gather1, ex1+h1b region is dead -> layer-2 buffers overlay h1b
    float* h2    = (float*)h1b;              // 40000*32
    float* asrc2 = h2 + 1280000;             // 40000
    float* adst2 = asrc2 + 40000;            // 40000
    float* agg2  = adst2 + 40000;            // 40000*32

    // Layer-1 GEMM first (also zeroes cnt for the histogram)
    gemm1_kernel<<<625, 256, 0, stream>>>(x, W1, a_src1, a_dst1, h1b, asrc1, adst1,
                                          (int4*)cnt);
    // CSR build (shared by both layers); fill also emits layer-1 edge numerators
    hist_kernel<<<(E_TOT + 255) / 256, 256, 0, stream>>>(eidx, cnt);
    scanA_kernel<<<SCAN_BLOCKS, 256, 0, stream>>>(cnt, rowptr, bsum, cursor);
    scanB_kernel<<<1, 256, 0, stream>>>(bsum);
    fill_kernel<<<(E_TOT + 255) / 256, 256, 0, stream>>>(
        eidx, rowptr, bsum, cursor, asrc1, adst1, esrc, ex1);

    // Layer 1 aggregate
    gather1_kernel<<<10000, 256, 0, stream>>>(rowptr, bsum, esrc, ex1, h1b, b1, agg1);

    // Layer 2
    gemm2_kernel<<<625, 256, 0, stream>>>(agg1, W2, a_src2, a_dst2, h2, asrc2, adst2);
    gather2_kernel<<<5000, 256, 0, stream>>>(rowptr, bsum, esrc, asrc2, adst2, h2, b2, agg2);

    // Output projection
    out_gemm_kernel<<<1250, 256, 0, stream>>>(agg2, W_out, b_out, out);
}